// Round 19
// baseline (2210.106 us; speedup 1.0000x reference)
//
#include <hip/hip_runtime.h>
#include <hip/hip_bf16.h>
#include <math.h>

// ---------------------------------------------------------------------------
// GIN model (GINEConv x5 + virtual node + readout).  [best: R18 1.999 ms]
// CSR message passing (per-wave node chains, packed-pair loads, 2-edge
// pipeline, R19: per-layer bond table staged in LDS — 20 KB, halves VMEM
// gathers per edge). CSR pooling with 4-node pipeline.
// All heavy GEMMs on bf16 MFMA: 128x128 tile, 8 waves, 3-buffer LDS pipeline
// (depth-2 prefetch, counted vmcnt(2), ONE barrier per K-step), XOR slot
// swizzle, XCD-chunked block swizzle. Pool GEMMs collapsed into one stacked
// GEMM; vn MLP on the MFMA path.
// NOTE (R12-R14): CH L2-residency cap regressed; 64-row band fusion
// regressed. GEMM structure is a protected local optimum.
// ---------------------------------------------------------------------------

typedef __hip_bfloat16 bf16;
typedef __attribute__((ext_vector_type(8))) __bf16 bf16x8;
typedef __attribute__((ext_vector_type(4))) float f32x4;

__device__ __forceinline__ float silu_f(float v) { return v / (1.0f + __expf(-v)); }
__device__ __forceinline__ float bfu_lo(unsigned u) {
    unsigned t = (u & 0xffffu) << 16; return *(float*)&t;
}
__device__ __forceinline__ float bfu_hi(unsigned u) {
    unsigned t = u & 0xffff0000u; return *(float*)&t;
}
__device__ __forceinline__ unsigned packbf(float a, float b) {
    bf16 x = __float2bfloat16(a), y = __float2bfloat16(b);
    return (unsigned)*(unsigned short*)&x | ((unsigned)*(unsigned short*)&y << 16);
}

// async global->LDS, 16B per lane; lds base must be wave-uniform.
#define GLOAD16(gp, lp) __builtin_amdgcn_global_load_lds( \
    (const __attribute__((address_space(1))) unsigned int*)(const void*)(gp), \
    (__attribute__((address_space(3))) unsigned int*)(void*)(lp), 16, 0, 0)

__global__ void k_fill(float* __restrict__ p, float v, int n) {
    int stride = gridDim.x * blockDim.x;
    for (int i = blockIdx.x * blockDim.x + threadIdx.x; i < n; i += stride) p[i] = v;
}

__global__ void k_zero(float* __restrict__ p, size_t n) {
    size_t stride = (size_t)gridDim.x * blockDim.x;
    for (size_t i = (size_t)blockIdx.x * blockDim.x + threadIdx.x; i < n; i += stride)
        p[i] = 0.0f;
}

// ---------------- CSR build helpers ----------------
__global__ void k_hist(const int* __restrict__ key, int* __restrict__ cnt, int n) {
    int stride = gridDim.x * blockDim.x;
    for (int i = blockIdx.x * blockDim.x + threadIdx.x; i < n; i += stride)
        atomicAdd(&cnt[key[i]], 1);
}

__global__ __launch_bounds__(256)
void k_scan1(const int* __restrict__ in, int* __restrict__ out,
             int* __restrict__ bsum, int n) {
    __shared__ int wsum[4];
    int base = blockIdx.x << 10;
    int t = threadIdx.x;
    int i0 = base + t * 4;
    int v0 = (i0 + 0 < n) ? in[i0 + 0] : 0;
    int v1 = (i0 + 1 < n) ? in[i0 + 1] : 0;
    int v2 = (i0 + 2 < n) ? in[i0 + 2] : 0;
    int v3 = (i0 + 3 < n) ? in[i0 + 3] : 0;
    int s = v0 + v1 + v2 + v3;
    int lane = t & 63, wid = t >> 6;
    int x = s;
    for (int d = 1; d < 64; d <<= 1) {
        int y = __shfl_up(x, d);
        if (lane >= d) x += y;
    }
    if (lane == 63) wsum[wid] = x;
    __syncthreads();
    int wadd = 0;
    for (int w = 0; w < wid; w++) wadd += wsum[w];
    x += wadd;
    int run = x - s;
    if (i0 + 0 < n) out[i0 + 0] = run; run += v0;
    if (i0 + 1 < n) out[i0 + 1] = run; run += v1;
    if (i0 + 2 < n) out[i0 + 2] = run; run += v2;
    if (i0 + 3 < n) out[i0 + 3] = run; run += v3;
    if (bsum && t == 255) bsum[blockIdx.x] = x;
}

__global__ void k_scan_add(int* __restrict__ out, const int* __restrict__ bsum,
                           int* __restrict__ cur, int n, int total) {
    int stride = gridDim.x * blockDim.x;
    for (int i = blockIdx.x * blockDim.x + threadIdx.x; i < n; i += stride) {
        int v = out[i] + bsum[i >> 10];
        out[i] = v;
        if (cur) cur[i] = v;
    }
    if (blockIdx.x == 0 && threadIdx.x == 0) out[n] = total;
}

__global__ void k_escatter(const int* __restrict__ dst, const int* __restrict__ src,
                           const int* __restrict__ ea, int* __restrict__ cur,
                           int* __restrict__ esrc, int* __restrict__ eea, int E) {
    int stride = gridDim.x * blockDim.x;
    for (int e = blockIdx.x * blockDim.x + threadIdx.x; e < E; e += stride) {
        int p = atomicAdd(&cur[dst[e]], 1);
        esrc[p] = src[e];
        eea[p]  = ea[e];
    }
}

// ---------------- model kernels ----------------
// tblb[l][a][j] = bf16( bond_emb[a].We[l][j] + be[l][j] ), zero-padded to KP1
__global__ void k_eptable(const float* __restrict__ bond_emb,
                          const float* __restrict__ We,
                          const float* __restrict__ be,
                          bf16* __restrict__ tblb, int BV, int H, int ED, int KP1) {
    int l = blockIdx.x / BV;
    int a = blockIdx.x % BV;
    int j = threadIdx.x;
    if (j >= KP1) return;
    float s = 0.0f;
    if (j < H) {
        const float* w = We + ((size_t)l * H + j) * ED;
        const float* bb = bond_emb + (size_t)a * ED;
        s = be[(size_t)l * H + j];
        for (int k = 0; k < ED; k++) s += bb[k] * w[k];
    }
    tblb[((size_t)l * BV + a) * KP1 + j] = __float2bfloat16(s);
}

__global__ void k_encode(const int* __restrict__ x, const float* __restrict__ emb,
                         bf16* __restrict__ h, int H, int total) {
    int stride = gridDim.x * blockDim.x;
    for (int i = blockIdx.x * blockDim.x + threadIdx.x; i < total; i += stride) {
        int n = i / H, j = i - n * H;
        h[i] = __float2bfloat16(emb[(size_t)x[n] * H + j]);
    }
}

// CSR message + zmix, ONE WAVE PER NODE, packed-pair loads, 2-edge pipeline.
// R19: per-layer bond table (BV x KP1 bf16, 20 KB) staged in LDS when it
// fits (<= 10240 shorts); per-edge tbl reads become conflict-free ds_read.
#define TBS_MAX 10240
__global__ __launch_bounds__(256)
void k_msg_csr(const int* __restrict__ eoff, const int* __restrict__ esrc,
               const int* __restrict__ eea, const bf16* __restrict__ h,
               const bf16* __restrict__ tblb, const float* __restrict__ epsp, int l,
               bf16* __restrict__ zb, int H, int KP1, int N, int BV) {
    __shared__ unsigned short tbs[TBS_MAX];
    const bool ldsok = (BV * KP1 <= TBS_MAX);
    if (ldsok) {
        const unsigned* srcw = (const unsigned*)tblb;
        unsigned* dstw = (unsigned*)tbs;
        int nw_ = (BV * KP1) >> 1;
        for (int i = threadIdx.x; i < nw_; i += blockDim.x) dstw[i] = srcw[i];
        __syncthreads();
    }
    const int wid = blockIdx.x * (blockDim.x >> 6) + (threadIdx.x >> 6);
    const int nw = gridDim.x * (blockDim.x >> 6);
    const int lane = threadIdx.x & 63;
    const float epl = 1.0f + epsp[l];
    const int c0 = 2 * lane;
    for (int n = wid; n < N; n += nw) {
        int e0 = eoff[n], e1 = eoff[n + 1];
        float a0[3] = {0.f, 0.f, 0.f}, a1[3] = {0.f, 0.f, 0.f};
        int e = e0;
        if (ldsok) {
            for (; e + 1 < e1; e += 2) {
                int sA = esrc[e],     aA = eea[e];
                int sB = esrc[e + 1], aB = eea[e + 1];
                const unsigned short* hrA = (const unsigned short*)h + (size_t)sA * H;
                const unsigned short* hrB = (const unsigned short*)h + (size_t)sB * H;
                const unsigned short* trA = tbs + aA * KP1;
                const unsigned short* trB = tbs + aB * KP1;
                unsigned hvA[3], tvA[3], hvB[3], tvB[3];
                #pragma unroll
                for (int p = 0; p < 3; p++) {
                    int c = c0 + p * 128;
                    if (c < H) {
                        hvA[p] = *(const unsigned*)(hrA + c);
                        hvB[p] = *(const unsigned*)(hrB + c);
                        tvA[p] = *(const unsigned*)(trA + c);
                        tvB[p] = *(const unsigned*)(trB + c);
                    }
                }
                #pragma unroll
                for (int p = 0; p < 3; p++) {
                    int c = c0 + p * 128;
                    if (c < H) {
                        float v0 = bfu_lo(hvA[p]) + bfu_lo(tvA[p]);
                        float v1 = bfu_hi(hvA[p]) + bfu_hi(tvA[p]);
                        if (v0 > 0.0f) a0[p] += v0;
                        if (v1 > 0.0f) a1[p] += v1;
                        float w0 = bfu_lo(hvB[p]) + bfu_lo(tvB[p]);
                        float w1 = bfu_hi(hvB[p]) + bfu_hi(tvB[p]);
                        if (w0 > 0.0f) a0[p] += w0;
                        if (w1 > 0.0f) a1[p] += w1;
                    }
                }
            }
            if (e < e1) {
                int s = esrc[e], a = eea[e];
                const unsigned short* hr = (const unsigned short*)h + (size_t)s * H;
                const unsigned short* tr = tbs + a * KP1;
                #pragma unroll
                for (int p = 0; p < 3; p++) {
                    int c = c0 + p * 128;
                    if (c < H) {
                        unsigned hv = *(const unsigned*)(hr + c);
                        unsigned tv = *(const unsigned*)(tr + c);
                        float v0 = bfu_lo(hv) + bfu_lo(tv);
                        float v1 = bfu_hi(hv) + bfu_hi(tv);
                        if (v0 > 0.0f) a0[p] += v0;
                        if (v1 > 0.0f) a1[p] += v1;
                    }
                }
            }
        } else {
            for (; e + 1 < e1; e += 2) {
                int sA = esrc[e],     aA = eea[e];
                int sB = esrc[e + 1], aB = eea[e + 1];
                const unsigned short* hrA = (const unsigned short*)h + (size_t)sA * H;
                const unsigned short* trA = (const unsigned short*)tblb + (size_t)aA * KP1;
                const unsigned short* hrB = (const unsigned short*)h + (size_t)sB * H;
                const unsigned short* trB = (const unsigned short*)tblb + (size_t)aB * KP1;
                unsigned hvA[3], tvA[3], hvB[3], tvB[3];
                #pragma unroll
                for (int p = 0; p < 3; p++) {
                    int c = c0 + p * 128;
                    if (c < H) {
                        hvA[p] = *(const unsigned*)(hrA + c);
                        tvA[p] = *(const unsigned*)(trA + c);
                        hvB[p] = *(const unsigned*)(hrB + c);
                        tvB[p] = *(const unsigned*)(trB + c);
                    }
                }
                #pragma unroll
                for (int p = 0; p < 3; p++) {
                    int c = c0 + p * 128;
                    if (c < H) {
                        float v0 = bfu_lo(hvA[p]) + bfu_lo(tvA[p]);
                        float v1 = bfu_hi(hvA[p]) + bfu_hi(tvA[p]);
                        if (v0 > 0.0f) a0[p] += v0;
                        if (v1 > 0.0f) a1[p] += v1;
                        float w0 = bfu_lo(hvB[p]) + bfu_lo(tvB[p]);
                        float w1 = bfu_hi(hvB[p]) + bfu_hi(tvB[p]);
                        if (w0 > 0.0f) a0[p] += w0;
                        if (w1 > 0.0f) a1[p] += w1;
                    }
                }
            }
            if (e < e1) {
                int s = esrc[e], a = eea[e];
                const unsigned short* hr = (const unsigned short*)h + (size_t)s * H;
                const unsigned short* tr = (const unsigned short*)tblb + (size_t)a * KP1;
                #pragma unroll
                for (int p = 0; p < 3; p++) {
                    int c = c0 + p * 128;
                    if (c < H) {
                        unsigned hv = *(const unsigned*)(hr + c);
                        unsigned tv = *(const unsigned*)(tr + c);
                        float v0 = bfu_lo(hv) + bfu_lo(tv);
                        float v1 = bfu_hi(hv) + bfu_hi(tv);
                        if (v0 > 0.0f) a0[p] += v0;
                        if (v1 > 0.0f) a1[p] += v1;
                    }
                }
            }
        }
        const unsigned short* hn = (const unsigned short*)h + (size_t)n * H;
        unsigned short* zr = (unsigned short*)zb + (size_t)n * KP1;
        #pragma unroll
        for (int p = 0; p < 3; p++) {
            int c = c0 + p * 128;
            if (c < KP1) {
                float z0 = 0.f, z1 = 0.f;
                if (c < H) {
                    unsigned hv = *(const unsigned*)(hn + c);
                    z0 = epl * bfu_lo(hv) + a0[p];
                    z1 = epl * bfu_hi(hv) + a1[p];
                }
                *(unsigned*)(zr + c) = packbf(z0, z1);
            }
        }
    }
}

// CSR pooling (batch sorted), packed pairs, 4-node software pipeline.
__global__ __launch_bounds__(256)
void k_pool_csr(const int* __restrict__ goff, const bf16* __restrict__ h,
                float* __restrict__ hp, bf16* __restrict__ hps, int layer, int KPS,
                int H, int G) {
    int j = threadIdx.x;
    int c = 2 * j;
    if (c >= H) return;
    for (int g = blockIdx.x; g < G; g += gridDim.x) {
        float s0 = 0.0f, s1 = 0.0f;
        int n0 = goff[g], n1 = goff[g + 1];
        const unsigned short* hb = (const unsigned short*)h;
        int n = n0;
        for (; n + 3 < n1; n += 4) {
            unsigned hv0 = *(const unsigned*)(hb + (size_t)(n + 0) * H + c);
            unsigned hv1 = *(const unsigned*)(hb + (size_t)(n + 1) * H + c);
            unsigned hv2 = *(const unsigned*)(hb + (size_t)(n + 2) * H + c);
            unsigned hv3 = *(const unsigned*)(hb + (size_t)(n + 3) * H + c);
            s0 += bfu_lo(hv0); s1 += bfu_hi(hv0);
            s0 += bfu_lo(hv1); s1 += bfu_hi(hv1);
            s0 += bfu_lo(hv2); s1 += bfu_hi(hv2);
            s0 += bfu_lo(hv3); s1 += bfu_hi(hv3);
        }
        for (; n < n1; n++) {
            unsigned hv = *(const unsigned*)(hb + (size_t)n * H + c);
            s0 += bfu_lo(hv);
            s1 += bfu_hi(hv);
        }
        hp[(size_t)g * H + c] = s0;
        hp[(size_t)g * H + c + 1] = s1;
        *(unsigned*)((unsigned short*)hps + (size_t)g * KPS + layer * H + c) = packbf(s0, s1);
    }
}

// h[n][c..c+1] += vn[batch[n]][c..c+1]   (pair-packed)
__global__ void k_addvn(bf16* __restrict__ h, const float* __restrict__ vn,
                        const int* __restrict__ batch, int H, int total2) {
    int stride = gridDim.x * blockDim.x;
    int HP = H >> 1;
    for (int i = blockIdx.x * blockDim.x + threadIdx.x; i < total2; i += stride) {
        int n = i / HP, p = i - n * HP;
        int c = 2 * p;
        unsigned short* hr = (unsigned short*)h + (size_t)n * H + c;
        unsigned hv = *(unsigned*)hr;
        const float* vr = vn + (size_t)batch[n] * H + c;
        *(unsigned*)hr = packbf(bfu_lo(hv) + vr[0], bfu_hi(hv) + vr[1]);
    }
}

// o[g][c] = bf16( (c<H) ? hp[g][c] + vn[g][c] : 0 ), c < KP
__global__ void k_add_castpad(const float* __restrict__ hp, const float* __restrict__ vn,
                              bf16* __restrict__ o, int H, int KP, int total) {
    int stride = gridDim.x * blockDim.x;
    for (int i = blockIdx.x * blockDim.x + threadIdx.x; i < total; i += stride) {
        int g = i / KP, c = i - g * KP;
        float v = 0.0f;
        if (c < H) v = hp[(size_t)g * H + c] + vn[(size_t)g * H + c];
        o[i] = __float2bfloat16(v);
    }
}

// weight cast + zero-pad for L layers: dst[l][r][c] (L x Rp x Kp)
__global__ void k_castw_all(const float* __restrict__ W, bf16* __restrict__ Wb,
                            int L, int R, int K, int Kp, int total) {
    int stride = gridDim.x * blockDim.x;
    int perL = R * K;
    for (int i = blockIdx.x * blockDim.x + threadIdx.x; i < total; i += stride) {
        int RpKp = total / L;
        int l = i / RpKp, rem = i - l * RpKp;
        int r = rem / Kp, c = rem - r * Kp;
        float v = (r < R && c < K) ? W[(size_t)l * perL + (size_t)r * K + c] : 0.0f;
        Wb[i] = __float2bfloat16(v);
    }
}

// stacked pooling weight: Wb[r][c] (Rp x KPS), value = Wp[c/H][r][c%H]
__global__ void k_castWps(const float* __restrict__ Wp, bf16* __restrict__ Wb,
                          int L, int H, int KPS, int total) {
    int stride = gridDim.x * blockDim.x;
    for (int i = blockIdx.x * blockDim.x + threadIdx.x; i < total; i += stride) {
        int r = i / KPS, c = i - r * KPS;
        float v = 0.0f;
        if (r < H && c < L * H) {
            int li = c / H, k = c - li * H;
            v = Wp[(size_t)li * H * H + (size_t)r * H + k];
        }
        Wb[i] = __float2bfloat16(v);
    }
}

// o[j] = sum_i bp[i*H+j]
__global__ void k_sumbias(const float* __restrict__ bp, float* __restrict__ o,
                          int L, int H) {
    int j = blockIdx.x * blockDim.x + threadIdx.x;
    if (j < H) {
        float s = 0.f;
        for (int i = 0; i < L; i++) s += bp[(size_t)i * H + j];
        o[j] = s;
    }
}

// --- MFMA GEMM: out[m,n] = epi( sum_k A[m,k]*B[n,k] ), A,B bf16 k-contig.
// 512 threads / 8 waves, tile 128x128, per-wave 32x64.
// 3-buffer LDS pipeline, depth-2 prefetch, counted vmcnt(2), ONE barrier per
// K-step. XOR slot swizzle both sides. XCD-chunked block swizzle.
__global__ __launch_bounds__(512)
void k_mfma_gemm(const bf16* __restrict__ A, const bf16* __restrict__ B,
                 const float* __restrict__ bias, const float* __restrict__ bn,
                 const bf16* __restrict__ resb, bf16* __restrict__ out,
                 float* __restrict__ outf,
                 int M, int Nc, int Kp, int ldA, int ldOut, int ldPad,
                 int dosilu, int ncol) {
    __shared__ short As[3 * 128 * 32];
    __shared__ short Bs[3 * 128 * 32];
    const int nwg = gridDim.x;
    const int bid = blockIdx.x;
    const int q = nwg >> 3, r = nwg & 7;
    const int xcd = bid & 7, ii = bid >> 3;
    const int wgid = (xcd < r ? xcd * (q + 1) : r * (q + 1) + (xcd - r) * q) + ii;
    const int rb = wgid / ncol, cb = wgid - rb * ncol;
    const int bm = rb * 128, bn0 = cb * 128;

    const int tid = threadIdx.x;
    const int wave = tid >> 6, lane = tid & 63;
    const int wr = wave >> 1, wc = wave & 1;
    const int l15 = lane & 15, l4 = lane >> 4;
    const int srow = wave * 16 + (lane >> 2);
    const int sslot = lane & 3;

    f32x4 acc[2][4];
    #pragma unroll
    for (int mi = 0; mi < 2; mi++)
        #pragma unroll
        for (int ni = 0; ni < 4; ni++)
            acc[mi][ni] = (f32x4){0.f, 0.f, 0.f, 0.f};

    const int sg = (sslot ^ ((srow >> 1) & 3)) << 3;

    auto STAGE = [&](int buf, int k0) {
        GLOAD16(A + (size_t)(bm + srow) * ldA + k0 + sg, As + buf * 4096 + wave * 512);
        GLOAD16(B + (size_t)(bn0 + srow) * Kp + k0 + sg, Bs + buf * 4096 + wave * 512);
    };

    const int nt = Kp >> 5;
    STAGE(0, 0);
    if (nt > 1) STAGE(1, 32);
    for (int t = 0; t < nt; ++t) {
        if (t + 1 < nt) asm volatile("s_waitcnt vmcnt(2)" ::: "memory");
        else            asm volatile("s_waitcnt vmcnt(0)" ::: "memory");
        __builtin_amdgcn_sched_barrier(0);
        __builtin_amdgcn_s_barrier();
        __builtin_amdgcn_sched_barrier(0);
        if (t + 2 < nt) STAGE((t + 2) % 3, (t + 2) << 5);
        const short* Ab = As + (t % 3) * 4096;
        const short* Bb = Bs + (t % 3) * 4096;
        bf16x8 a[2], b[4];
        #pragma unroll
        for (int mi = 0; mi < 2; mi++) {
            int row = wr * 32 + mi * 16 + l15;
            a[mi] = *(const bf16x8*)&Ab[row * 32 + ((l4 ^ ((row >> 1) & 3)) << 3)];
        }
        #pragma unroll
        for (int ni = 0; ni < 4; ni++) {
            int row = wc * 64 + ni * 16 + l15;
            b[ni] = *(const bf16x8*)&Bb[row * 32 + ((l4 ^ ((row >> 1) & 3)) << 3)];
        }
        #pragma unroll
        for (int mi = 0; mi < 2; mi++)
            #pragma unroll
            for (int ni = 0; ni < 4; ni++)
                acc[mi][ni] = __builtin_amdgcn_mfma_f32_16x16x32_bf16(
                    a[mi], b[ni], acc[mi][ni], 0, 0, 0);
        __builtin_amdgcn_sched_barrier(0);
    }

    #pragma unroll
    for (int ni = 0; ni < 4; ni++) {
        int col = bn0 + wc * 64 + ni * 16 + l15;
        if (col >= ldPad) continue;
        bool pad = (col >= Nc);
        float bi = (!pad && bias) ? bias[col] : 0.f;
        float sc = 1.f, mm = 0.f, bb = 0.f;
        if (!pad && bn) {
            sc = bn[col] * rsqrtf(bn[3 * Nc + col] + 1e-5f);
            mm = bn[2 * Nc + col];
            bb = bn[Nc + col];
        }
        #pragma unroll
        for (int mi = 0; mi < 2; mi++) {
            #pragma unroll
            for (int rr = 0; rr < 4; rr++) {
                int row = bm + wr * 32 + mi * 16 + l4 * 4 + rr;
                if (row >= M) continue;
                size_t idx = (size_t)row * ldOut + col;
                if (outf) {
                    if (pad) continue;
                    float v = acc[mi][ni][rr] + bi;
                    if (bn) v = (v - mm) * sc + bb;
                    if (dosilu) v = silu_f(v);
                    outf[idx] = v;
                } else {
                    if (pad) { out[idx] = __float2bfloat16(0.f); continue; }
                    float v = acc[mi][ni][rr] + bi;
                    if (bn) v = (v - mm) * sc + bb;
                    if (dosilu) v = silu_f(v);
                    if (resb) v += __bfloat162float(resb[idx]);
                    out[idx] = __float2bfloat16(v);
                }
            }
        }
    }
}

// --- small fp32 GEMM (readout only)
#define GBM 64
#define GBN 64
#define GBK 16
__global__ __launch_bounds__(256)
void k_gemm(const float* __restrict__ A, const float* __restrict__ B,
            const float* __restrict__ bias, const float* __restrict__ bn,
            float* __restrict__ C, int M, int Nc, int K, int flags) {
    __shared__ float As[GBK][GBM + 4];
    __shared__ float Bs[GBK][GBN + 4];
    const int bm = blockIdx.x * GBM;
    const int bnc = blockIdx.y * GBN;
    const int tid = threadIdx.x;
    const int tx = tid & 15, ty = tid >> 4;
    const int ar = tid >> 2;
    const int ak = (tid & 3) << 2;

    float acc[4][4] = {{0.f}};

    for (int k0 = 0; k0 < K; k0 += GBK) {
        {
            int gr = bm + ar, gk = k0 + ak;
            float4 v = make_float4(0.f, 0.f, 0.f, 0.f);
            if (gr < M && gk < K) {
                const float* p = A + (size_t)gr * K;
                if (gk + 3 < K) v = *(const float4*)(p + gk);
                else {
                    v.x = p[gk];
                    if (gk + 1 < K) v.y = p[gk + 1];
                    if (gk + 2 < K) v.z = p[gk + 2];
                }
            }
            As[ak][ar] = v.x; As[ak + 1][ar] = v.y; As[ak + 2][ar] = v.z; As[ak + 3][ar] = v.w;
        }
        {
            int gr = bnc + ar, gk = k0 + ak;
            float4 v = make_float4(0.f, 0.f, 0.f, 0.f);
            if (gr < Nc && gk < K) {
                const float* p = B + (size_t)gr * K;
                if (gk + 3 < K) v = *(const float4*)(p + gk);
                else {
                    v.x = p[gk];
                    if (gk + 1 < K) v.y = p[gk + 1];
                    if (gk + 2 < K) v.z = p[gk + 2];
                }
            }
            Bs[ak][ar] = v.x; Bs[ak + 1][ar] = v.y; Bs[ak + 2][ar] = v.z; Bs[ak + 3][ar] = v.w;
        }
        __syncthreads();
        #pragma unroll
        for (int kk = 0; kk < GBK; kk++) {
            float4 a = *(const float4*)&As[kk][ty * 4];
            float4 b = *(const float4*)&Bs[kk][tx * 4];
            acc[0][0] += a.x * b.x; acc[0][1] += a.x * b.y; acc[0][2] += a.x * b.z; acc[0][3] += a.x * b.w;
            acc[1][0] += a.y * b.x; acc[1][1] += a.y * b.y; acc[1][2] += a.y * b.z; acc[1][3] += a.y * b.w;
            acc[2][0] += a.z * b.x; acc[2][1] += a.z * b.y; acc[2][2] += a.z * b.z; acc[2][3] += a.z * b.w;
            acc[3][0] += a.w * b.x; acc[3][1] += a.w * b.y; acc[3][2] += a.w * b.z; acc[3][3] += a.w * b.w;
        }
        __syncthreads();
    }

    #pragma unroll
    for (int i = 0; i < 4; i++) {
        int row = bm + ty * 4 + i;
        if (row >= M) continue;
        #pragma unroll
        for (int j = 0; j < 4; j++) {
            int col = bnc + tx * 4 + j;
            if (col >= Nc) continue;
            float v = acc[i][j];
            if (bias) v += bias[col];
            if (bn) {
                float g = bn[col], bb = bn[Nc + col], mm = bn[2 * Nc + col], vv = bn[3 * Nc + col];
                v = (v - mm) * (g * rsqrtf(vv + 1e-5f)) + bb;
            }
            if (flags & 1) v = silu_f(v);
            size_t idx = (size_t)row * Nc + col;
            if (flags & 2) C[idx] += v;
            else           C[idx] = v;
        }
    }
}

// per-row LayerNorm + SiLU
__global__ __launch_bounds__(256)
void k_ln_silu(const float* __restrict__ hg, const float* __restrict__ g,
               const float* __restrict__ b, float* __restrict__ r, int H) {
    int gi = blockIdx.x;
    const float* row = hg + (size_t)gi * H;
    float s = 0.f, s2 = 0.f;
    for (int j = threadIdx.x; j < H; j += blockDim.x) {
        float v = row[j];
        s += v; s2 += v * v;
    }
    for (int off = 32; off; off >>= 1) {
        s += __shfl_down(s, off);
        s2 += __shfl_down(s2, off);
    }
    __shared__ float rs[4], rs2[4];
    int wid = threadIdx.x >> 6, lane = threadIdx.x & 63;
    if (lane == 0) { rs[wid] = s; rs2[wid] = s2; }
    __syncthreads();
    if (threadIdx.x == 0) {
        float S = 0.f, S2 = 0.f;
        for (int w = 0; w < 4; w++) { S += rs[w]; S2 += rs2[w]; }
        rs[0] = S; rs2[0] = S2;
    }
    __syncthreads();
    float mu = rs[0] / H;
    float var = rs2[0] / H - mu * mu;
    float inv = rsqrtf(var + 1e-5f);
    for (int j = threadIdx.x; j < H; j += blockDim.x) {
        float v = (row[j] - mu) * inv * g[j] + b[j];
        r[(size_t)gi * H + j] = silu_f(v);
    }
}

__global__ void k_head2(const float* __restrict__ r2, const float* __restrict__ w,
                        const float* __restrict__ b, float* __restrict__ out, int Kh) {
    int gi = blockIdx.x;
    int t = threadIdx.x;
    float s = 0.f;
    for (int k = t; k < Kh; k += 64) s += r2[(size_t)gi * Kh + k] * w[k];
    for (int off = 32; off; off >>= 1) s += __shfl_down(s, off);
    if (t == 0) out[gi] = s + b[0];
}

extern "C" void kernel_launch(void* const* d_in, const int* in_sizes, int n_in,
                              void* d_out, int out_size, void* d_ws, size_t ws_size,
                              hipStream_t stream) {
    const int*   x         = (const int*)d_in[0];
    const int*   edge_attr = (const int*)d_in[1];
    const int*   eidx      = (const int*)d_in[2];
    const int*   batch     = (const int*)d_in[3];
    const float* atom_emb  = (const float*)d_in[5];
    const float* bond_emb  = (const float*)d_in[6];
    const float* We  = (const float*)d_in[7];
    const float* be  = (const float*)d_in[8];
    const float* W1  = (const float*)d_in[9];
    const float* b1  = (const float*)d_in[10];
    const float* bn1 = (const float*)d_in[11];
    const float* W2  = (const float*)d_in[12];
    const float* b2  = (const float*)d_in[13];
    const float* bn2 = (const float*)d_in[14];
    const float* epsp= (const float*)d_in[15];
    const float* Wp  = (const float*)d_in[16];
    const float* bp  = (const float*)d_in[17];
    const float* vnW1= (const float*)d_in[18];
    const float* vnb1= (const float*)d_in[19];
    const float* vnbn= (const float*)d_in[20];
    const float* vnW2= (const float*)d_in[21];
    const float* vnb2= (const float*)d_in[22];
    const float* ln_g= (const float*)d_in[23];
    const float* ln_b= (const float*)d_in[24];
    const float* hW1 = (const float*)d_in[25];
    const float* hb1 = (const float*)d_in[26];
    const float* hW2 = (const float*)d_in[27];
    const float* hb2 = (const float*)d_in[28];
    float* out = (float*)d_out;

    const int N  = in_sizes[0];
    const int E  = in_sizes[1];
    const int G  = out_size;
    const int L  = in_sizes[15];
    const int H  = in_sizes[19];
    const int H2 = 2 * H;
    const int ED = in_sizes[7] / (L * H);
    const int BV = in_sizes[6] / ED;
    const int HH = in_sizes[26];
    (void)n_in;

    const int* src = eidx;
    const int* dst = eidx + E;

    // padded dims for MFMA path
    const int KP1 = ((H  + 31) / 32) * 32;            // 320
    const int KP2 = ((H2 + 31) / 32) * 32;            // 608
    const int KPS = ((L * H + 31) / 32) * 32;         // 1504
    const int RP1 = ((H2 + 127) / 128) * 128;         // 640
    const int RP2 = ((H  + 127) / 128) * 128;         // 384
    const int Npad = ((N + 127) / 128) * 128;
    const int GP   = ((G + 127) / 128) * 128;         // 4096

    // ---- workspace carve-up (bytes, 256B aligned), strictly within ws_size ----
    char* wsb = (char*)d_ws;
    auto alb = [](size_t v) { return (v + 255) & ~(size_t)255; };
    const size_t fN = (size_t)N * H;
    const size_t fG = (size_t)G * H;

    size_t off = 0;
    bf16*  hbf   = (bf16*) (wsb + off); off += alb(fN * 2);
    bf16*  zb    = (bf16*) (wsb + off); off += alb((size_t)Npad * KP1 * 2);
    float* hp    = (float*)(wsb + off); off += alb(fG * 4);
    float* hg    = (float*)(wsb + off); off += alb(fG * 4);
    float* vn    = (float*)(wsb + off); off += alb(fG * 4);
    float* rbuf  = (float*)(wsb + off); off += alb(fG * 4);
    float* r2    = (float*)(wsb + off); off += alb((size_t)G * HH * 4);
    bf16*  tblb  = (bf16*) (wsb + off); off += alb((size_t)L * BV * KP1 * 2);
    float* bsumf = (float*)(wsb + off); off += alb((size_t)RP2 * 4);
    bf16*  W1b   = (bf16*) (wsb + off); off += alb((size_t)L * RP1 * KP1 * 2);
    bf16*  W2b   = (bf16*) (wsb + off); off += alb((size_t)L * RP2 * KP2 * 2);
    bf16*  vnW1b = (bf16*) (wsb + off); off += alb((size_t)RP2 * KP1 * 2);
    bf16*  vnW2b = (bf16*) (wsb + off); off += alb((size_t)RP2 * KP1 * 2);
    bf16*  Wpsb  = (bf16*) (wsb + off); off += alb((size_t)RP2 * KPS * 2);
    bf16*  hps   = (bf16*) (wsb + off); off += alb((size_t)GP * KPS * 2);
    bf16*  vninb = (bf16*) (wsb + off); off += alb((size_t)GP * KP1 * 2);
    bf16*  vntb  = (bf16*) (wsb + off); off += alb((size_t)GP * KP1 * 2);
    // CSR arrays (ints)
    int* eoff = (int*)(wsb + off); off += alb((size_t)(N + 1) * 4);
    int* ecur = (int*)(wsb + off); off += alb((size_t)N * 4);
    int* esrc = (int*)(wsb + off); off += alb((size_t)E * 4);
    int* eea  = (int*)(wsb + off); off += alb((size_t)E * 4);
    int* goff = (int*)(wsb + off); off += alb((size_t)(G + 1) * 4);
    int* gcnt = (int*)(wsb + off); off += alb((size_t)G * 4);
    int* bsum = (int*)(wsb + off); off += alb(1024 * 4);

    // t1 chunk region gets the rest
    size_t left = (ws_size > off + 256) ? (ws_size - off - 256) : 0;
    long long chl = (long long)(left / ((size_t)KP2 * 2));
    int CH = (int)((chl > Npad) ? Npad : chl);
    CH = (CH / 128) * 128;
    if (CH < 128) {
        k_fill<<<64, 256, 0, stream>>>(out, 10000.0f + (float)(ws_size >> 20), G);
        return;
    }
    bf16* t1 = (bf16*)(wsb + off);

    auto gemm_f = [&](const float* A, const float* B, const float* bias, const float* bn,
                      float* C, int M, int Nc, int K, int flags) {
        dim3 grid((M + GBM - 1) / GBM, (Nc + GBN - 1) / GBN);
        k_gemm<<<grid, dim3(256), 0, stream>>>(A, B, bias, bn, C, M, Nc, K, flags);
    };
    auto mfma = [&](const bf16* A, const bf16* B, const float* bias, const float* bn,
                    const bf16* resb, bf16* outb, float* outf, int M, int Nc, int Kp,
                    int ldA, int ldOut, int ldPad, int dosilu, int ncolT) {
        int mt = (M + 127) / 128;
        k_mfma_gemm<<<dim3(mt * ncolT), dim3(512), 0, stream>>>(
            A, B, bias, bn, resb, outb, outf, M, Nc, Kp, ldA, ldOut, ldPad, dosilu, ncolT);
    };
    auto zero = [&](void* p, size_t nfloats) { k_zero<<<1024, 256, 0, stream>>>((float*)p, nfloats); };

    const int NH = N * H;

    // ---- CSR builds (dst and batch are layer-invariant) ----
    {
        int nb = (N + 1023) / 1024;
        zero(ecur, N);
        k_hist<<<1024, 256, 0, stream>>>(dst, ecur, E);
        k_scan1<<<nb, 256, 0, stream>>>(ecur, eoff, bsum, N);
        k_scan1<<<1, 256, 0, stream>>>(bsum, bsum, nullptr, nb);
        k_scan_add<<<512, 256, 0, stream>>>(eoff, bsum, ecur, N, E);
        k_escatter<<<1024, 256, 0, stream>>>(dst, src, edge_attr, ecur, esrc, eea, E);

        int nbg = (G + 1023) / 1024;
        zero(gcnt, G);
        k_hist<<<1024, 256, 0, stream>>>(batch, gcnt, N);
        k_scan1<<<nbg, 256, 0, stream>>>(gcnt, goff, bsum, G);
        k_scan1<<<1, 256, 0, stream>>>(bsum, bsum, nullptr, nbg);
        k_scan_add<<<64, 256, 0, stream>>>(goff, bsum, nullptr, G, N);
    }

    zero(vn, fG);
    zero(hps, (size_t)GP * KPS / 2);   // bf16 buffer: bytes/4 floats

    k_eptable<<<L * BV, 320, 0, stream>>>(bond_emb, We, be, tblb, BV, H, ED, KP1);
    k_encode<<<2048, 256, 0, stream>>>(x, atom_emb, hbf, H, NH);
    // weight casts (once per launch)
    k_castw_all<<<2048, 256, 0, stream>>>(W1, W1b, L, H2, H, KP1, L * RP1 * KP1);
    k_castw_all<<<2048, 256, 0, stream>>>(W2, W2b, L, H, H2, KP2, L * RP2 * KP2);
    k_castw_all<<<256, 256, 0, stream>>>(vnW1, vnW1b, 1, H, H, KP1, RP2 * KP1);
    k_castw_all<<<256, 256, 0, stream>>>(vnW2, vnW2b, 1, H, H, KP1, RP2 * KP1);
    k_castWps<<<512, 256, 0, stream>>>(Wp, Wpsb, L, H, KPS, RP2 * KPS);
    k_sumbias<<<(H + 255) / 256, 256, 0, stream>>>(bp, bsumf, L, H);

    for (int i = 0; i < L; i++) {
        if (i > 0) {
            // vn MLP on MFMA path
            k_add_castpad<<<2048, 256, 0, stream>>>(hp, vn, vninb, H, KP1, G * KP1);
            mfma(vninb, vnW1b, vnb1, vnbn, nullptr, vntb, nullptr,
                 G, H, KP1, KP1, KP1, KP1, 1, RP2 / 128);
            mfma(vntb, vnW2b, vnb2, nullptr, nullptr, nullptr, vn,
                 G, H, KP1, KP1, H, H, 0, RP2 / 128);
            k_addvn<<<2048, 256, 0, stream>>>(hbf, vn, batch, H, N * (H >> 1));
        }
        // fused message + zmix (one wave per node, 2-edge pipeline, LDS tbl)
        k_msg_csr<<<4096, 256, 0, stream>>>(eoff, esrc, eea, hbf,
                                            tblb + (size_t)i * BV * KP1, epsp, i,
                                            zb, H, KP1, N, BV);
        // node MLP, row-chunked through t1
        for (int r0 = 0; r0 < N; r0 += CH) {
            int m = (N - r0 < CH) ? (N - r0) : CH;
            mfma(zb + (size_t)r0 * KP1, W1b + (size_t)i * RP1 * KP1,
                 b1 + (size_t)i * H2, bn1 + (size_t)i * 4 * H2,
                 nullptr, t1, nullptr, m, H2, KP1, KP1, KP2, KP2, 1, RP1 / 128);
            mfma(t1, W2b + (size_t)i * RP2 * KP2, b2 + (size_t)i * H,
                 bn2 + (size_t)i * 4 * H,
                 (i > 0) ? (hbf + (size_t)r0 * H) : nullptr, hbf + (size_t)r0 * H,
                 nullptr, m, H, KP2, KP2, H, H, 1, RP2 / 128);
        }
        // CSR pooling: hp fp32 + bf16 slice into layer-stacked hps
        k_pool_csr<<<4096, 256, 0, stream>>>(goff, hbf, hp, hps, i, KPS, H, G);
    }

    // hg = hps @ Wps^T + sum(bp)  (single stacked GEMM, fp32 out)
    mfma(hps, Wpsb, bsumf, nullptr, nullptr, nullptr, hg,
         G, H, KPS, KPS, H, H, 0, RP2 / 128);

    // readout
    k_ln_silu<<<G, 256, 0, stream>>>(hg, ln_g, ln_b, rbuf, H);
    gemm_f(rbuf, hW1, hb1, nullptr, r2, G, HH, H, 1);
    k_head2<<<G, 64, 0, stream>>>(r2, hW2, hb2, out, HH);
}

// Round 20
// 1995.564 us; speedup vs baseline: 1.1075x; 1.1075x over previous
//
#include <hip/hip_runtime.h>
#include <hip/hip_bf16.h>
#include <math.h>

// ---------------------------------------------------------------------------
// GIN model (GINEConv x5 + virtual node + readout).  [R18 best: 1.999 ms]
// CSR message passing (per-wave node chains, packed-pair loads, bf16 tbl,
// 2-edge software pipeline; direct tbl reads — R19's LDS-staged tbl regressed:
// occupancy 59->42%, per-block staging cost >> reuse at ~25 nodes/block).
// CSR pooling with 4-node pipeline.
// All heavy GEMMs on bf16 MFMA: 128x128 tile, 8 waves, 3-buffer LDS pipeline
// (depth-2 prefetch, counted vmcnt(2), ONE barrier per K-step), XOR slot
// swizzle, XCD-chunked block swizzle. Pool GEMMs collapsed into one stacked
// GEMM; vn MLP on the MFMA path.
// NOTE (R12-R14): CH L2-residency cap regressed; 64-row band fusion
// regressed. GEMM structure is a protected local optimum.
// ---------------------------------------------------------------------------

typedef __hip_bfloat16 bf16;
typedef __attribute__((ext_vector_type(8))) __bf16 bf16x8;
typedef __attribute__((ext_vector_type(4))) float f32x4;

__device__ __forceinline__ float silu_f(float v) { return v / (1.0f + __expf(-v)); }
__device__ __forceinline__ float bfu_lo(unsigned u) {
    unsigned t = (u & 0xffffu) << 16; return *(float*)&t;
}
__device__ __forceinline__ float bfu_hi(unsigned u) {
    unsigned t = u & 0xffff0000u; return *(float*)&t;
}
__device__ __forceinline__ unsigned packbf(float a, float b) {
    bf16 x = __float2bfloat16(a), y = __float2bfloat16(b);
    return (unsigned)*(unsigned short*)&x | ((unsigned)*(unsigned short*)&y << 16);
}

// async global->LDS, 16B per lane; lds base must be wave-uniform.
#define GLOAD16(gp, lp) __builtin_amdgcn_global_load_lds( \
    (const __attribute__((address_space(1))) unsigned int*)(const void*)(gp), \
    (__attribute__((address_space(3))) unsigned int*)(void*)(lp), 16, 0, 0)

__global__ void k_fill(float* __restrict__ p, float v, int n) {
    int stride = gridDim.x * blockDim.x;
    for (int i = blockIdx.x * blockDim.x + threadIdx.x; i < n; i += stride) p[i] = v;
}

__global__ void k_zero(float* __restrict__ p, size_t n) {
    size_t stride = (size_t)gridDim.x * blockDim.x;
    for (size_t i = (size_t)blockIdx.x * blockDim.x + threadIdx.x; i < n; i += stride)
        p[i] = 0.0f;
}

// ---------------- CSR build helpers ----------------
__global__ void k_hist(const int* __restrict__ key, int* __restrict__ cnt, int n) {
    int stride = gridDim.x * blockDim.x;
    for (int i = blockIdx.x * blockDim.x + threadIdx.x; i < n; i += stride)
        atomicAdd(&cnt[key[i]], 1);
}

__global__ __launch_bounds__(256)
void k_scan1(const int* __restrict__ in, int* __restrict__ out,
             int* __restrict__ bsum, int n) {
    __shared__ int wsum[4];
    int base = blockIdx.x << 10;
    int t = threadIdx.x;
    int i0 = base + t * 4;
    int v0 = (i0 + 0 < n) ? in[i0 + 0] : 0;
    int v1 = (i0 + 1 < n) ? in[i0 + 1] : 0;
    int v2 = (i0 + 2 < n) ? in[i0 + 2] : 0;
    int v3 = (i0 + 3 < n) ? in[i0 + 3] : 0;
    int s = v0 + v1 + v2 + v3;
    int lane = t & 63, wid = t >> 6;
    int x = s;
    for (int d = 1; d < 64; d <<= 1) {
        int y = __shfl_up(x, d);
        if (lane >= d) x += y;
    }
    if (lane == 63) wsum[wid] = x;
    __syncthreads();
    int wadd = 0;
    for (int w = 0; w < wid; w++) wadd += wsum[w];
    x += wadd;
    int run = x - s;
    if (i0 + 0 < n) out[i0 + 0] = run; run += v0;
    if (i0 + 1 < n) out[i0 + 1] = run; run += v1;
    if (i0 + 2 < n) out[i0 + 2] = run; run += v2;
    if (i0 + 3 < n) out[i0 + 3] = run; run += v3;
    if (bsum && t == 255) bsum[blockIdx.x] = x;
}

__global__ void k_scan_add(int* __restrict__ out, const int* __restrict__ bsum,
                           int* __restrict__ cur, int n, int total) {
    int stride = gridDim.x * blockDim.x;
    for (int i = blockIdx.x * blockDim.x + threadIdx.x; i < n; i += stride) {
        int v = out[i] + bsum[i >> 10];
        out[i] = v;
        if (cur) cur[i] = v;
    }
    if (blockIdx.x == 0 && threadIdx.x == 0) out[n] = total;
}

__global__ void k_escatter(const int* __restrict__ dst, const int* __restrict__ src,
                           const int* __restrict__ ea, int* __restrict__ cur,
                           int* __restrict__ esrc, int* __restrict__ eea, int E) {
    int stride = gridDim.x * blockDim.x;
    for (int e = blockIdx.x * blockDim.x + threadIdx.x; e < E; e += stride) {
        int p = atomicAdd(&cur[dst[e]], 1);
        esrc[p] = src[e];
        eea[p]  = ea[e];
    }
}

// ---------------- model kernels ----------------
// tblb[l][a][j] = bf16( bond_emb[a].We[l][j] + be[l][j] ), zero-padded to KP1
__global__ void k_eptable(const float* __restrict__ bond_emb,
                          const float* __restrict__ We,
                          const float* __restrict__ be,
                          bf16* __restrict__ tblb, int BV, int H, int ED, int KP1) {
    int l = blockIdx.x / BV;
    int a = blockIdx.x % BV;
    int j = threadIdx.x;
    if (j >= KP1) return;
    float s = 0.0f;
    if (j < H) {
        const float* w = We + ((size_t)l * H + j) * ED;
        const float* bb = bond_emb + (size_t)a * ED;
        s = be[(size_t)l * H + j];
        for (int k = 0; k < ED; k++) s += bb[k] * w[k];
    }
    tblb[((size_t)l * BV + a) * KP1 + j] = __float2bfloat16(s);
}

__global__ void k_encode(const int* __restrict__ x, const float* __restrict__ emb,
                         bf16* __restrict__ h, int H, int total) {
    int stride = gridDim.x * blockDim.x;
    for (int i = blockIdx.x * blockDim.x + threadIdx.x; i < total; i += stride) {
        int n = i / H, j = i - n * H;
        h[i] = __float2bfloat16(emb[(size_t)x[n] * H + j]);
    }
}

// CSR message + zmix, ONE WAVE PER NODE, packed-pair loads,
// 2-edge software pipeline (batch both edges' gathers before accumulating;
// accumulation order preserved: edge e then e+1).
__global__ __launch_bounds__(256)
void k_msg_csr(const int* __restrict__ eoff, const int* __restrict__ esrc,
               const int* __restrict__ eea, const bf16* __restrict__ h,
               const bf16* __restrict__ tblb, const float* __restrict__ epsp, int l,
               bf16* __restrict__ zb, int H, int KP1, int N) {
    const int wid = blockIdx.x * (blockDim.x >> 6) + (threadIdx.x >> 6);
    const int nw = gridDim.x * (blockDim.x >> 6);
    const int lane = threadIdx.x & 63;
    const float epl = 1.0f + epsp[l];
    const int c0 = 2 * lane;
    for (int n = wid; n < N; n += nw) {
        int e0 = eoff[n], e1 = eoff[n + 1];
        float a0[3] = {0.f, 0.f, 0.f}, a1[3] = {0.f, 0.f, 0.f};
        int e = e0;
        for (; e + 1 < e1; e += 2) {
            int sA = esrc[e],     aA = eea[e];
            int sB = esrc[e + 1], aB = eea[e + 1];
            const unsigned short* hrA = (const unsigned short*)h + (size_t)sA * H;
            const unsigned short* trA = (const unsigned short*)tblb + (size_t)aA * KP1;
            const unsigned short* hrB = (const unsigned short*)h + (size_t)sB * H;
            const unsigned short* trB = (const unsigned short*)tblb + (size_t)aB * KP1;
            unsigned hvA[3], tvA[3], hvB[3], tvB[3];
            #pragma unroll
            for (int p = 0; p < 3; p++) {
                int c = c0 + p * 128;
                if (c < H) {
                    hvA[p] = *(const unsigned*)(hrA + c);
                    tvA[p] = *(const unsigned*)(trA + c);
                    hvB[p] = *(const unsigned*)(hrB + c);
                    tvB[p] = *(const unsigned*)(trB + c);
                }
            }
            #pragma unroll
            for (int p = 0; p < 3; p++) {
                int c = c0 + p * 128;
                if (c < H) {
                    float v0 = bfu_lo(hvA[p]) + bfu_lo(tvA[p]);
                    float v1 = bfu_hi(hvA[p]) + bfu_hi(tvA[p]);
                    if (v0 > 0.0f) a0[p] += v0;
                    if (v1 > 0.0f) a1[p] += v1;
                    float w0 = bfu_lo(hvB[p]) + bfu_lo(tvB[p]);
                    float w1 = bfu_hi(hvB[p]) + bfu_hi(tvB[p]);
                    if (w0 > 0.0f) a0[p] += w0;
                    if (w1 > 0.0f) a1[p] += w1;
                }
            }
        }
        if (e < e1) {
            int s = esrc[e], a = eea[e];
            const unsigned short* hr = (const unsigned short*)h + (size_t)s * H;
            const unsigned short* tr = (const unsigned short*)tblb + (size_t)a * KP1;
            #pragma unroll
            for (int p = 0; p < 3; p++) {
                int c = c0 + p * 128;
                if (c < H) {
                    unsigned hv = *(const unsigned*)(hr + c);
                    unsigned tv = *(const unsigned*)(tr + c);
                    float v0 = bfu_lo(hv) + bfu_lo(tv);
                    float v1 = bfu_hi(hv) + bfu_hi(tv);
                    if (v0 > 0.0f) a0[p] += v0;
                    if (v1 > 0.0f) a1[p] += v1;
                }
            }
        }
        const unsigned short* hn = (const unsigned short*)h + (size_t)n * H;
        unsigned short* zr = (unsigned short*)zb + (size_t)n * KP1;
        #pragma unroll
        for (int p = 0; p < 3; p++) {
            int c = c0 + p * 128;
            if (c < KP1) {
                float z0 = 0.f, z1 = 0.f;
                if (c < H) {
                    unsigned hv = *(const unsigned*)(hn + c);
                    z0 = epl * bfu_lo(hv) + a0[p];
                    z1 = epl * bfu_hi(hv) + a1[p];
                }
                *(unsigned*)(zr + c) = packbf(z0, z1);
            }
        }
    }
}

// CSR pooling (batch sorted), packed pairs, 4-node software pipeline.
__global__ __launch_bounds__(256)
void k_pool_csr(const int* __restrict__ goff, const bf16* __restrict__ h,
                float* __restrict__ hp, bf16* __restrict__ hps, int layer, int KPS,
                int H, int G) {
    int j = threadIdx.x;
    int c = 2 * j;
    if (c >= H) return;
    for (int g = blockIdx.x; g < G; g += gridDim.x) {
        float s0 = 0.0f, s1 = 0.0f;
        int n0 = goff[g], n1 = goff[g + 1];
        const unsigned short* hb = (const unsigned short*)h;
        int n = n0;
        for (; n + 3 < n1; n += 4) {
            unsigned hv0 = *(const unsigned*)(hb + (size_t)(n + 0) * H + c);
            unsigned hv1 = *(const unsigned*)(hb + (size_t)(n + 1) * H + c);
            unsigned hv2 = *(const unsigned*)(hb + (size_t)(n + 2) * H + c);
            unsigned hv3 = *(const unsigned*)(hb + (size_t)(n + 3) * H + c);
            s0 += bfu_lo(hv0); s1 += bfu_hi(hv0);
            s0 += bfu_lo(hv1); s1 += bfu_hi(hv1);
            s0 += bfu_lo(hv2); s1 += bfu_hi(hv2);
            s0 += bfu_lo(hv3); s1 += bfu_hi(hv3);
        }
        for (; n < n1; n++) {
            unsigned hv = *(const unsigned*)(hb + (size_t)n * H + c);
            s0 += bfu_lo(hv);
            s1 += bfu_hi(hv);
        }
        hp[(size_t)g * H + c] = s0;
        hp[(size_t)g * H + c + 1] = s1;
        *(unsigned*)((unsigned short*)hps + (size_t)g * KPS + layer * H + c) = packbf(s0, s1);
    }
}

// h[n][c..c+1] += vn[batch[n]][c..c+1]   (pair-packed)
__global__ void k_addvn(bf16* __restrict__ h, const float* __restrict__ vn,
                        const int* __restrict__ batch, int H, int total2) {
    int stride = gridDim.x * blockDim.x;
    int HP = H >> 1;
    for (int i = blockIdx.x * blockDim.x + threadIdx.x; i < total2; i += stride) {
        int n = i / HP, p = i - n * HP;
        int c = 2 * p;
        unsigned short* hr = (unsigned short*)h + (size_t)n * H + c;
        unsigned hv = *(unsigned*)hr;
        const float* vr = vn + (size_t)batch[n] * H + c;
        *(unsigned*)hr = packbf(bfu_lo(hv) + vr[0], bfu_hi(hv) + vr[1]);
    }
}

// o[g][c] = bf16( (c<H) ? hp[g][c] + vn[g][c] : 0 ), c < KP
__global__ void k_add_castpad(const float* __restrict__ hp, const float* __restrict__ vn,
                              bf16* __restrict__ o, int H, int KP, int total) {
    int stride = gridDim.x * blockDim.x;
    for (int i = blockIdx.x * blockDim.x + threadIdx.x; i < total; i += stride) {
        int g = i / KP, c = i - g * KP;
        float v = 0.0f;
        if (c < H) v = hp[(size_t)g * H + c] + vn[(size_t)g * H + c];
        o[i] = __float2bfloat16(v);
    }
}

// weight cast + zero-pad for L layers: dst[l][r][c] (L x Rp x Kp)
__global__ void k_castw_all(const float* __restrict__ W, bf16* __restrict__ Wb,
                            int L, int R, int K, int Kp, int total) {
    int stride = gridDim.x * blockDim.x;
    int perL = R * K;
    for (int i = blockIdx.x * blockDim.x + threadIdx.x; i < total; i += stride) {
        int RpKp = total / L;
        int l = i / RpKp, rem = i - l * RpKp;
        int r = rem / Kp, c = rem - r * Kp;
        float v = (r < R && c < K) ? W[(size_t)l * perL + (size_t)r * K + c] : 0.0f;
        Wb[i] = __float2bfloat16(v);
    }
}

// stacked pooling weight: Wb[r][c] (Rp x KPS), value = Wp[c/H][r][c%H]
__global__ void k_castWps(const float* __restrict__ Wp, bf16* __restrict__ Wb,
                          int L, int H, int KPS, int total) {
    int stride = gridDim.x * blockDim.x;
    for (int i = blockIdx.x * blockDim.x + threadIdx.x; i < total; i += stride) {
        int r = i / KPS, c = i - r * KPS;
        float v = 0.0f;
        if (r < H && c < L * H) {
            int li = c / H, k = c - li * H;
            v = Wp[(size_t)li * H * H + (size_t)r * H + k];
        }
        Wb[i] = __float2bfloat16(v);
    }
}

// o[j] = sum_i bp[i*H+j]
__global__ void k_sumbias(const float* __restrict__ bp, float* __restrict__ o,
                          int L, int H) {
    int j = blockIdx.x * blockDim.x + threadIdx.x;
    if (j < H) {
        float s = 0.f;
        for (int i = 0; i < L; i++) s += bp[(size_t)i * H + j];
        o[j] = s;
    }
}

// --- MFMA GEMM: out[m,n] = epi( sum_k A[m,k]*B[n,k] ), A,B bf16 k-contig.
// 512 threads / 8 waves, tile 128x128, per-wave 32x64.
// 3-buffer LDS pipeline, depth-2 prefetch, counted vmcnt(2), ONE barrier per
// K-step. XOR slot swizzle both sides. XCD-chunked block swizzle.
__global__ __launch_bounds__(512)
void k_mfma_gemm(const bf16* __restrict__ A, const bf16* __restrict__ B,
                 const float* __restrict__ bias, const float* __restrict__ bn,
                 const bf16* __restrict__ resb, bf16* __restrict__ out,
                 float* __restrict__ outf,
                 int M, int Nc, int Kp, int ldA, int ldOut, int ldPad,
                 int dosilu, int ncol) {
    __shared__ short As[3 * 128 * 32];
    __shared__ short Bs[3 * 128 * 32];
    const int nwg = gridDim.x;
    const int bid = blockIdx.x;
    const int q = nwg >> 3, r = nwg & 7;
    const int xcd = bid & 7, ii = bid >> 3;
    const int wgid = (xcd < r ? xcd * (q + 1) : r * (q + 1) + (xcd - r) * q) + ii;
    const int rb = wgid / ncol, cb = wgid - rb * ncol;
    const int bm = rb * 128, bn0 = cb * 128;

    const int tid = threadIdx.x;
    const int wave = tid >> 6, lane = tid & 63;
    const int wr = wave >> 1, wc = wave & 1;
    const int l15 = lane & 15, l4 = lane >> 4;
    const int srow = wave * 16 + (lane >> 2);
    const int sslot = lane & 3;

    f32x4 acc[2][4];
    #pragma unroll
    for (int mi = 0; mi < 2; mi++)
        #pragma unroll
        for (int ni = 0; ni < 4; ni++)
            acc[mi][ni] = (f32x4){0.f, 0.f, 0.f, 0.f};

    const int sg = (sslot ^ ((srow >> 1) & 3)) << 3;

    auto STAGE = [&](int buf, int k0) {
        GLOAD16(A + (size_t)(bm + srow) * ldA + k0 + sg, As + buf * 4096 + wave * 512);
        GLOAD16(B + (size_t)(bn0 + srow) * Kp + k0 + sg, Bs + buf * 4096 + wave * 512);
    };

    const int nt = Kp >> 5;
    STAGE(0, 0);
    if (nt > 1) STAGE(1, 32);
    for (int t = 0; t < nt; ++t) {
        if (t + 1 < nt) asm volatile("s_waitcnt vmcnt(2)" ::: "memory");
        else            asm volatile("s_waitcnt vmcnt(0)" ::: "memory");
        __builtin_amdgcn_sched_barrier(0);
        __builtin_amdgcn_s_barrier();
        __builtin_amdgcn_sched_barrier(0);
        if (t + 2 < nt) STAGE((t + 2) % 3, (t + 2) << 5);
        const short* Ab = As + (t % 3) * 4096;
        const short* Bb = Bs + (t % 3) * 4096;
        bf16x8 a[2], b[4];
        #pragma unroll
        for (int mi = 0; mi < 2; mi++) {
            int row = wr * 32 + mi * 16 + l15;
            a[mi] = *(const bf16x8*)&Ab[row * 32 + ((l4 ^ ((row >> 1) & 3)) << 3)];
        }
        #pragma unroll
        for (int ni = 0; ni < 4; ni++) {
            int row = wc * 64 + ni * 16 + l15;
            b[ni] = *(const bf16x8*)&Bb[row * 32 + ((l4 ^ ((row >> 1) & 3)) << 3)];
        }
        #pragma unroll
        for (int mi = 0; mi < 2; mi++)
            #pragma unroll
            for (int ni = 0; ni < 4; ni++)
                acc[mi][ni] = __builtin_amdgcn_mfma_f32_16x16x32_bf16(
                    a[mi], b[ni], acc[mi][ni], 0, 0, 0);
        __builtin_amdgcn_sched_barrier(0);
    }

    #pragma unroll
    for (int ni = 0; ni < 4; ni++) {
        int col = bn0 + wc * 64 + ni * 16 + l15;
        if (col >= ldPad) continue;
        bool pad = (col >= Nc);
        float bi = (!pad && bias) ? bias[col] : 0.f;
        float sc = 1.f, mm = 0.f, bb = 0.f;
        if (!pad && bn) {
            sc = bn[col] * rsqrtf(bn[3 * Nc + col] + 1e-5f);
            mm = bn[2 * Nc + col];
            bb = bn[Nc + col];
        }
        #pragma unroll
        for (int mi = 0; mi < 2; mi++) {
            #pragma unroll
            for (int rr = 0; rr < 4; rr++) {
                int row = bm + wr * 32 + mi * 16 + l4 * 4 + rr;
                if (row >= M) continue;
                size_t idx = (size_t)row * ldOut + col;
                if (outf) {
                    if (pad) continue;
                    float v = acc[mi][ni][rr] + bi;
                    if (bn) v = (v - mm) * sc + bb;
                    if (dosilu) v = silu_f(v);
                    outf[idx] = v;
                } else {
                    if (pad) { out[idx] = __float2bfloat16(0.f); continue; }
                    float v = acc[mi][ni][rr] + bi;
                    if (bn) v = (v - mm) * sc + bb;
                    if (dosilu) v = silu_f(v);
                    if (resb) v += __bfloat162float(resb[idx]);
                    out[idx] = __float2bfloat16(v);
                }
            }
        }
    }
}

// --- small fp32 GEMM (readout only)
#define GBM 64
#define GBN 64
#define GBK 16
__global__ __launch_bounds__(256)
void k_gemm(const float* __restrict__ A, const float* __restrict__ B,
            const float* __restrict__ bias, const float* __restrict__ bn,
            float* __restrict__ C, int M, int Nc, int K, int flags) {
    __shared__ float As[GBK][GBM + 4];
    __shared__ float Bs[GBK][GBN + 4];
    const int bm = blockIdx.x * GBM;
    const int bnc = blockIdx.y * GBN;
    const int tid = threadIdx.x;
    const int tx = tid & 15, ty = tid >> 4;
    const int ar = tid >> 2;
    const int ak = (tid & 3) << 2;

    float acc[4][4] = {{0.f}};

    for (int k0 = 0; k0 < K; k0 += GBK) {
        {
            int gr = bm + ar, gk = k0 + ak;
            float4 v = make_float4(0.f, 0.f, 0.f, 0.f);
            if (gr < M && gk < K) {
                const float* p = A + (size_t)gr * K;
                if (gk + 3 < K) v = *(const float4*)(p + gk);
                else {
                    v.x = p[gk];
                    if (gk + 1 < K) v.y = p[gk + 1];
                    if (gk + 2 < K) v.z = p[gk + 2];
                }
            }
            As[ak][ar] = v.x; As[ak + 1][ar] = v.y; As[ak + 2][ar] = v.z; As[ak + 3][ar] = v.w;
        }
        {
            int gr = bnc + ar, gk = k0 + ak;
            float4 v = make_float4(0.f, 0.f, 0.f, 0.f);
            if (gr < Nc && gk < K) {
                const float* p = B + (size_t)gr * K;
                if (gk + 3 < K) v = *(const float4*)(p + gk);
                else {
                    v.x = p[gk];
                    if (gk + 1 < K) v.y = p[gk + 1];
                    if (gk + 2 < K) v.z = p[gk + 2];
                }
            }
            Bs[ak][ar] = v.x; Bs[ak + 1][ar] = v.y; Bs[ak + 2][ar] = v.z; Bs[ak + 3][ar] = v.w;
        }
        __syncthreads();
        #pragma unroll
        for (int kk = 0; kk < GBK; kk++) {
            float4 a = *(const float4*)&As[kk][ty * 4];
            float4 b = *(const float4*)&Bs[kk][tx * 4];
            acc[0][0] += a.x * b.x; acc[0][1] += a.x * b.y; acc[0][2] += a.x * b.z; acc[0][3] += a.x * b.w;
            acc[1][0] += a.y * b.x; acc[1][1] += a.y * b.y; acc[1][2] += a.y * b.z; acc[1][3] += a.y * b.w;
            acc[2][0] += a.z * b.x; acc[2][1] += a.z * b.y; acc[2][2] += a.z * b.z; acc[2][3] += a.z * b.w;
            acc[3][0] += a.w * b.x; acc[3][1] += a.w * b.y; acc[3][2] += a.w * b.z; acc[3][3] += a.w * b.w;
        }
        __syncthreads();
    }

    #pragma unroll
    for (int i = 0; i < 4; i++) {
        int row = bm + ty * 4 + i;
        if (row >= M) continue;
        #pragma unroll
        for (int j = 0; j < 4; j++) {
            int col = bnc + tx * 4 + j;
            if (col >= Nc) continue;
            float v = acc[i][j];
            if (bias) v += bias[col];
            if (bn) {
                float g = bn[col], bb = bn[Nc + col], mm = bn[2 * Nc + col], vv = bn[3 * Nc + col];
                v = (v - mm) * (g * rsqrtf(vv + 1e-5f)) + bb;
            }
            if (flags & 1) v = silu_f(v);
            size_t idx = (size_t)row * Nc + col;
            if (flags & 2) C[idx] += v;
            else           C[idx] = v;
        }
    }
}

// per-row LayerNorm + SiLU
__global__ __launch_bounds__(256)
void k_ln_silu(const float* __restrict__ hg, const float* __restrict__ g,
               const float* __restrict__ b, float* __restrict__ r, int H) {
    int gi = blockIdx.x;
    const float* row = hg + (size_t)gi * H;
    float s = 0.f, s2 = 0.f;
    for (int j = threadIdx.x; j < H; j += blockDim.x) {
        float v = row[j];
        s += v; s2 += v * v;
    }
    for (int off = 32; off; off >>= 1) {
        s += __shfl_down(s, off);
        s2 += __shfl_down(s2, off);
    }
    __shared__ float rs[4], rs2[4];
    int wid = threadIdx.x >> 6, lane = threadIdx.x & 63;
    if (lane == 0) { rs[wid] = s; rs2[wid] = s2; }
    __syncthreads();
    if (threadIdx.x == 0) {
        float S = 0.f, S2 = 0.f;
        for (int w = 0; w < 4; w++) { S += rs[w]; S2 += rs2[w]; }
        rs[0] = S; rs2[0] = S2;
    }
    __syncthreads();
    float mu = rs[0] / H;
    float var = rs2[0] / H - mu * mu;
    float inv = rsqrtf(var + 1e-5f);
    for (int j = threadIdx.x; j < H; j += blockDim.x) {
        float v = (row[j] - mu) * inv * g[j] + b[j];
        r[(size_t)gi * H + j] = silu_f(v);
    }
}

__global__ void k_head2(const float* __restrict__ r2, const float* __restrict__ w,
                        const float* __restrict__ b, float* __restrict__ out, int Kh) {
    int gi = blockIdx.x;
    int t = threadIdx.x;
    float s = 0.f;
    for (int k = t; k < Kh; k += 64) s += r2[(size_t)gi * Kh + k] * w[k];
    for (int off = 32; off; off >>= 1) s += __shfl_down(s, off);
    if (t == 0) out[gi] = s + b[0];
}

extern "C" void kernel_launch(void* const* d_in, const int* in_sizes, int n_in,
                              void* d_out, int out_size, void* d_ws, size_t ws_size,
                              hipStream_t stream) {
    const int*   x         = (const int*)d_in[0];
    const int*   edge_attr = (const int*)d_in[1];
    const int*   eidx      = (const int*)d_in[2];
    const int*   batch     = (const int*)d_in[3];
    const float* atom_emb  = (const float*)d_in[5];
    const float* bond_emb  = (const float*)d_in[6];
    const float* We  = (const float*)d_in[7];
    const float* be  = (const float*)d_in[8];
    const float* W1  = (const float*)d_in[9];
    const float* b1  = (const float*)d_in[10];
    const float* bn1 = (const float*)d_in[11];
    const float* W2  = (const float*)d_in[12];
    const float* b2  = (const float*)d_in[13];
    const float* bn2 = (const float*)d_in[14];
    const float* epsp= (const float*)d_in[15];
    const float* Wp  = (const float*)d_in[16];
    const float* bp  = (const float*)d_in[17];
    const float* vnW1= (const float*)d_in[18];
    const float* vnb1= (const float*)d_in[19];
    const float* vnbn= (const float*)d_in[20];
    const float* vnW2= (const float*)d_in[21];
    const float* vnb2= (const float*)d_in[22];
    const float* ln_g= (const float*)d_in[23];
    const float* ln_b= (const float*)d_in[24];
    const float* hW1 = (const float*)d_in[25];
    const float* hb1 = (const float*)d_in[26];
    const float* hW2 = (const float*)d_in[27];
    const float* hb2 = (const float*)d_in[28];
    float* out = (float*)d_out;

    const int N  = in_sizes[0];
    const int E  = in_sizes[1];
    const int G  = out_size;
    const int L  = in_sizes[15];
    const int H  = in_sizes[19];
    const int H2 = 2 * H;
    const int ED = in_sizes[7] / (L * H);
    const int BV = in_sizes[6] / ED;
    const int HH = in_sizes[26];
    (void)n_in;

    const int* src = eidx;
    const int* dst = eidx + E;

    // padded dims for MFMA path
    const int KP1 = ((H  + 31) / 32) * 32;            // 320
    const int KP2 = ((H2 + 31) / 32) * 32;            // 608
    const int KPS = ((L * H + 31) / 32) * 32;         // 1504
    const int RP1 = ((H2 + 127) / 128) * 128;         // 640
    const int RP2 = ((H  + 127) / 128) * 128;         // 384
    const int Npad = ((N + 127) / 128) * 128;
    const int GP   = ((G + 127) / 128) * 128;         // 4096

    // ---- workspace carve-up (bytes, 256B aligned), strictly within ws_size ----
    char* wsb = (char*)d_ws;
    auto alb = [](size_t v) { return (v + 255) & ~(size_t)255; };
    const size_t fN = (size_t)N * H;
    const size_t fG = (size_t)G * H;

    size_t off = 0;
    bf16*  hbf   = (bf16*) (wsb + off); off += alb(fN * 2);
    bf16*  zb    = (bf16*) (wsb + off); off += alb((size_t)Npad * KP1 * 2);
    float* hp    = (float*)(wsb + off); off += alb(fG * 4);
    float* hg    = (float*)(wsb + off); off += alb(fG * 4);
    float* vn    = (float*)(wsb + off); off += alb(fG * 4);
    float* rbuf  = (float*)(wsb + off); off += alb(fG * 4);
    float* r2    = (float*)(wsb + off); off += alb((size_t)G * HH * 4);
    bf16*  tblb  = (bf16*) (wsb + off); off += alb((size_t)L * BV * KP1 * 2);
    float* bsumf = (float*)(wsb + off); off += alb((size_t)RP2 * 4);
    bf16*  W1b   = (bf16*) (wsb + off); off += alb((size_t)L * RP1 * KP1 * 2);
    bf16*  W2b   = (bf16*) (wsb + off); off += alb((size_t)L * RP2 * KP2 * 2);
    bf16*  vnW1b = (bf16*) (wsb + off); off += alb((size_t)RP2 * KP1 * 2);
    bf16*  vnW2b = (bf16*) (wsb + off); off += alb((size_t)RP2 * KP1 * 2);
    bf16*  Wpsb  = (bf16*) (wsb + off); off += alb((size_t)RP2 * KPS * 2);
    bf16*  hps   = (bf16*) (wsb + off); off += alb((size_t)GP * KPS * 2);
    bf16*  vninb = (bf16*) (wsb + off); off += alb((size_t)GP * KP1 * 2);
    bf16*  vntb  = (bf16*) (wsb + off); off += alb((size_t)GP * KP1 * 2);
    // CSR arrays (ints)
    int* eoff = (int*)(wsb + off); off += alb((size_t)(N + 1) * 4);
    int* ecur = (int*)(wsb + off); off += alb((size_t)N * 4);
    int* esrc = (int*)(wsb + off); off += alb((size_t)E * 4);
    int* eea  = (int*)(wsb + off); off += alb((size_t)E * 4);
    int* goff = (int*)(wsb + off); off += alb((size_t)(G + 1) * 4);
    int* gcnt = (int*)(wsb + off); off += alb((size_t)G * 4);
    int* bsum = (int*)(wsb + off); off += alb(1024 * 4);

    // t1 chunk region gets the rest
    size_t left = (ws_size > off + 256) ? (ws_size - off - 256) : 0;
    long long chl = (long long)(left / ((size_t)KP2 * 2));
    int CH = (int)((chl > Npad) ? Npad : chl);
    CH = (CH / 128) * 128;
    if (CH < 128) {
        k_fill<<<64, 256, 0, stream>>>(out, 10000.0f + (float)(ws_size >> 20), G);
        return;
    }
    bf16* t1 = (bf16*)(wsb + off);

    auto gemm_f = [&](const float* A, const float* B, const float* bias, const float* bn,
                      float* C, int M, int Nc, int K, int flags) {
        dim3 grid((M + GBM - 1) / GBM, (Nc + GBN - 1) / GBN);
        k_gemm<<<grid, dim3(256), 0, stream>>>(A, B, bias, bn, C, M, Nc, K, flags);
    };
    auto mfma = [&](const bf16* A, const bf16* B, const float* bias, const float* bn,
                    const bf16* resb, bf16* outb, float* outf, int M, int Nc, int Kp,
                    int ldA, int ldOut, int ldPad, int dosilu, int ncolT) {
        int mt = (M + 127) / 128;
        k_mfma_gemm<<<dim3(mt * ncolT), dim3(512), 0, stream>>>(
            A, B, bias, bn, resb, outb, outf, M, Nc, Kp, ldA, ldOut, ldPad, dosilu, ncolT);
    };
    auto zero = [&](void* p, size_t nfloats) { k_zero<<<1024, 256, 0, stream>>>((float*)p, nfloats); };

    const int NH = N * H;

    // ---- CSR builds (dst and batch are layer-invariant) ----
    {
        int nb = (N + 1023) / 1024;
        zero(ecur, N);
        k_hist<<<1024, 256, 0, stream>>>(dst, ecur, E);
        k_scan1<<<nb, 256, 0, stream>>>(ecur, eoff, bsum, N);
        k_scan1<<<1, 256, 0, stream>>>(bsum, bsum, nullptr, nb);
        k_scan_add<<<512, 256, 0, stream>>>(eoff, bsum, ecur, N, E);
        k_escatter<<<1024, 256, 0, stream>>>(dst, src, edge_attr, ecur, esrc, eea, E);

        int nbg = (G + 1023) / 1024;
        zero(gcnt, G);
        k_hist<<<1024, 256, 0, stream>>>(batch, gcnt, N);
        k_scan1<<<nbg, 256, 0, stream>>>(gcnt, goff, bsum, G);
        k_scan1<<<1, 256, 0, stream>>>(bsum, bsum, nullptr, nbg);
        k_scan_add<<<64, 256, 0, stream>>>(goff, bsum, nullptr, G, N);
    }

    zero(vn, fG);
    zero(hps, (size_t)GP * KPS / 2);   // bf16 buffer: bytes/4 floats

    k_eptable<<<L * BV, 320, 0, stream>>>(bond_emb, We, be, tblb, BV, H, ED, KP1);
    k_encode<<<2048, 256, 0, stream>>>(x, atom_emb, hbf, H, NH);
    // weight casts (once per launch)
    k_castw_all<<<2048, 256, 0, stream>>>(W1, W1b, L, H2, H, KP1, L * RP1 * KP1);
    k_castw_all<<<2048, 256, 0, stream>>>(W2, W2b, L, H, H2, KP2, L * RP2 * KP2);
    k_castw_all<<<256, 256, 0, stream>>>(vnW1, vnW1b, 1, H, H, KP1, RP2 * KP1);
    k_castw_all<<<256, 256, 0, stream>>>(vnW2, vnW2b, 1, H, H, KP1, RP2 * KP1);
    k_castWps<<<512, 256, 0, stream>>>(Wp, Wpsb, L, H, KPS, RP2 * KPS);
    k_sumbias<<<(H + 255) / 256, 256, 0, stream>>>(bp, bsumf, L, H);

    for (int i = 0; i < L; i++) {
        if (i > 0) {
            // vn MLP on MFMA path
            k_add_castpad<<<2048, 256, 0, stream>>>(hp, vn, vninb, H, KP1, G * KP1);
            mfma(vninb, vnW1b, vnb1, vnbn, nullptr, vntb, nullptr,
                 G, H, KP1, KP1, KP1, KP1, 1, RP2 / 128);
            mfma(vntb, vnW2b, vnb2, nullptr, nullptr, nullptr, vn,
                 G, H, KP1, KP1, H, H, 0, RP2 / 128);
            k_addvn<<<2048, 256, 0, stream>>>(hbf, vn, batch, H, N * (H >> 1));
        }
        // fused message + zmix (one wave per node, packed loads, 2-edge pipeline)
        k_msg_csr<<<4096, 256, 0, stream>>>(eoff, esrc, eea, hbf,
                                            tblb + (size_t)i * BV * KP1, epsp, i,
                                            zb, H, KP1, N);
        // node MLP, row-chunked through t1
        for (int r0 = 0; r0 < N; r0 += CH) {
            int m = (N - r0 < CH) ? (N - r0) : CH;
            mfma(zb + (size_t)r0 * KP1, W1b + (size_t)i * RP1 * KP1,
                 b1 + (size_t)i * H2, bn1 + (size_t)i * 4 * H2,
                 nullptr, t1, nullptr, m, H2, KP1, KP1, KP2, KP2, 1, RP1 / 128);
            mfma(t1, W2b + (size_t)i * RP2 * KP2, b2 + (size_t)i * H,
                 bn2 + (size_t)i * 4 * H,
                 (i > 0) ? (hbf + (size_t)r0 * H) : nullptr, hbf + (size_t)r0 * H,
                 nullptr, m, H, KP2, KP2, H, H, 1, RP2 / 128);
        }
        // CSR pooling: hp fp32 + bf16 slice into layer-stacked hps
        k_pool_csr<<<4096, 256, 0, stream>>>(goff, hbf, hp, hps, i, KPS, H, G);
    }

    // hg = hps @ Wps^T + sum(bp)  (single stacked GEMM, fp32 out)
    mfma(hps, Wpsb, bsumf, nullptr, nullptr, nullptr, hg,
         G, H, KPS, KPS, H, H, 0, RP2 / 128);

    // readout
    k_ln_silu<<<G, 256, 0, stream>>>(hg, ln_g, ln_b, rbuf, H);
    gemm_f(rbuf, hW1, hb1, nullptr, r2, G, HH, H, 1);
    k_head2<<<G, 64, 0, stream>>>(r2, hW2, hb2, out, HH);
}

// Round 21
// 1988.906 us; speedup vs baseline: 1.1112x; 1.0033x over previous
//
#include <hip/hip_runtime.h>
#include <hip/hip_bf16.h>
#include <math.h>

// ---------------------------------------------------------------------------
// GIN model (GINEConv x5 + virtual node + readout).  [R18/R20: 1.996 ms]
// CSR message passing (per-wave node chains, packed-pair loads, bf16 tbl,
// 2-edge software pipeline). CSR pooling with 4-node pipeline, R21: fused
// vninb = bf16(hp + vn) emission (deletes k_add_castpad dispatches; bit-exact
// because vn is final for the next layer when pool runs).
// All heavy GEMMs on bf16 MFMA: 128x128 tile, 8 waves, 3-buffer LDS pipeline
// (depth-2 prefetch, counted vmcnt(2), ONE barrier per K-step), XOR slot
// swizzle, XCD-chunked block swizzle. Pool GEMMs collapsed into one stacked
// GEMM; vn MLP on the MFMA path.
// NOTE (R12-R14, R19): CH L2-residency cap, 64-row band fusion, and LDS-tbl
// staging all regressed. GEMM + msg structures are protected local optima.
// ---------------------------------------------------------------------------

typedef __hip_bfloat16 bf16;
typedef __attribute__((ext_vector_type(8))) __bf16 bf16x8;
typedef __attribute__((ext_vector_type(4))) float f32x4;

__device__ __forceinline__ float silu_f(float v) { return v / (1.0f + __expf(-v)); }
__device__ __forceinline__ float bfu_lo(unsigned u) {
    unsigned t = (u & 0xffffu) << 16; return *(float*)&t;
}
__device__ __forceinline__ float bfu_hi(unsigned u) {
    unsigned t = u & 0xffff0000u; return *(float*)&t;
}
__device__ __forceinline__ unsigned packbf(float a, float b) {
    bf16 x = __float2bfloat16(a), y = __float2bfloat16(b);
    return (unsigned)*(unsigned short*)&x | ((unsigned)*(unsigned short*)&y << 16);
}

// async global->LDS, 16B per lane; lds base must be wave-uniform.
#define GLOAD16(gp, lp) __builtin_amdgcn_global_load_lds( \
    (const __attribute__((address_space(1))) unsigned int*)(const void*)(gp), \
    (__attribute__((address_space(3))) unsigned int*)(void*)(lp), 16, 0, 0)

__global__ void k_fill(float* __restrict__ p, float v, int n) {
    int stride = gridDim.x * blockDim.x;
    for (int i = blockIdx.x * blockDim.x + threadIdx.x; i < n; i += stride) p[i] = v;
}

__global__ void k_zero(float* __restrict__ p, size_t n) {
    size_t stride = (size_t)gridDim.x * blockDim.x;
    for (size_t i = (size_t)blockIdx.x * blockDim.x + threadIdx.x; i < n; i += stride)
        p[i] = 0.0f;
}

// ---------------- CSR build helpers ----------------
__global__ void k_hist(const int* __restrict__ key, int* __restrict__ cnt, int n) {
    int stride = gridDim.x * blockDim.x;
    for (int i = blockIdx.x * blockDim.x + threadIdx.x; i < n; i += stride)
        atomicAdd(&cnt[key[i]], 1);
}

__global__ __launch_bounds__(256)
void k_scan1(const int* __restrict__ in, int* __restrict__ out,
             int* __restrict__ bsum, int n) {
    __shared__ int wsum[4];
    int base = blockIdx.x << 10;
    int t = threadIdx.x;
    int i0 = base + t * 4;
    int v0 = (i0 + 0 < n) ? in[i0 + 0] : 0;
    int v1 = (i0 + 1 < n) ? in[i0 + 1] : 0;
    int v2 = (i0 + 2 < n) ? in[i0 + 2] : 0;
    int v3 = (i0 + 3 < n) ? in[i0 + 3] : 0;
    int s = v0 + v1 + v2 + v3;
    int lane = t & 63, wid = t >> 6;
    int x = s;
    for (int d = 1; d < 64; d <<= 1) {
        int y = __shfl_up(x, d);
        if (lane >= d) x += y;
    }
    if (lane == 63) wsum[wid] = x;
    __syncthreads();
    int wadd = 0;
    for (int w = 0; w < wid; w++) wadd += wsum[w];
    x += wadd;
    int run = x - s;
    if (i0 + 0 < n) out[i0 + 0] = run; run += v0;
    if (i0 + 1 < n) out[i0 + 1] = run; run += v1;
    if (i0 + 2 < n) out[i0 + 2] = run; run += v2;
    if (i0 + 3 < n) out[i0 + 3] = run; run += v3;
    if (bsum && t == 255) bsum[blockIdx.x] = x;
}

__global__ void k_scan_add(int* __restrict__ out, const int* __restrict__ bsum,
                           int* __restrict__ cur, int n, int total) {
    int stride = gridDim.x * blockDim.x;
    for (int i = blockIdx.x * blockDim.x + threadIdx.x; i < n; i += stride) {
        int v = out[i] + bsum[i >> 10];
        out[i] = v;
        if (cur) cur[i] = v;
    }
    if (blockIdx.x == 0 && threadIdx.x == 0) out[n] = total;
}

__global__ void k_escatter(const int* __restrict__ dst, const int* __restrict__ src,
                           const int* __restrict__ ea, int* __restrict__ cur,
                           int* __restrict__ esrc, int* __restrict__ eea, int E) {
    int stride = gridDim.x * blockDim.x;
    for (int e = blockIdx.x * blockDim.x + threadIdx.x; e < E; e += stride) {
        int p = atomicAdd(&cur[dst[e]], 1);
        esrc[p] = src[e];
        eea[p]  = ea[e];
    }
}

// ---------------- model kernels ----------------
// tblb[l][a][j] = bf16( bond_emb[a].We[l][j] + be[l][j] ), zero-padded to KP1
__global__ void k_eptable(const float* __restrict__ bond_emb,
                          const float* __restrict__ We,
                          const float* __restrict__ be,
                          bf16* __restrict__ tblb, int BV, int H, int ED, int KP1) {
    int l = blockIdx.x / BV;
    int a = blockIdx.x % BV;
    int j = threadIdx.x;
    if (j >= KP1) return;
    float s = 0.0f;
    if (j < H) {
        const float* w = We + ((size_t)l * H + j) * ED;
        const float* bb = bond_emb + (size_t)a * ED;
        s = be[(size_t)l * H + j];
        for (int k = 0; k < ED; k++) s += bb[k] * w[k];
    }
    tblb[((size_t)l * BV + a) * KP1 + j] = __float2bfloat16(s);
}

__global__ void k_encode(const int* __restrict__ x, const float* __restrict__ emb,
                         bf16* __restrict__ h, int H, int total) {
    int stride = gridDim.x * blockDim.x;
    for (int i = blockIdx.x * blockDim.x + threadIdx.x; i < total; i += stride) {
        int n = i / H, j = i - n * H;
        h[i] = __float2bfloat16(emb[(size_t)x[n] * H + j]);
    }
}

// CSR message + zmix, ONE WAVE PER NODE, packed-pair loads,
// 2-edge software pipeline (accumulation order preserved: edge e then e+1).
__global__ __launch_bounds__(256)
void k_msg_csr(const int* __restrict__ eoff, const int* __restrict__ esrc,
               const int* __restrict__ eea, const bf16* __restrict__ h,
               const bf16* __restrict__ tblb, const float* __restrict__ epsp, int l,
               bf16* __restrict__ zb, int H, int KP1, int N) {
    const int wid = blockIdx.x * (blockDim.x >> 6) + (threadIdx.x >> 6);
    const int nw = gridDim.x * (blockDim.x >> 6);
    const int lane = threadIdx.x & 63;
    const float epl = 1.0f + epsp[l];
    const int c0 = 2 * lane;
    for (int n = wid; n < N; n += nw) {
        int e0 = eoff[n], e1 = eoff[n + 1];
        float a0[3] = {0.f, 0.f, 0.f}, a1[3] = {0.f, 0.f, 0.f};
        int e = e0;
        for (; e + 1 < e1; e += 2) {
            int sA = esrc[e],     aA = eea[e];
            int sB = esrc[e + 1], aB = eea[e + 1];
            const unsigned short* hrA = (const unsigned short*)h + (size_t)sA * H;
            const unsigned short* trA = (const unsigned short*)tblb + (size_t)aA * KP1;
            const unsigned short* hrB = (const unsigned short*)h + (size_t)sB * H;
            const unsigned short* trB = (const unsigned short*)tblb + (size_t)aB * KP1;
            unsigned hvA[3], tvA[3], hvB[3], tvB[3];
            #pragma unroll
            for (int p = 0; p < 3; p++) {
                int c = c0 + p * 128;
                if (c < H) {
                    hvA[p] = *(const unsigned*)(hrA + c);
                    tvA[p] = *(const unsigned*)(trA + c);
                    hvB[p] = *(const unsigned*)(hrB + c);
                    tvB[p] = *(const unsigned*)(trB + c);
                }
            }
            #pragma unroll
            for (int p = 0; p < 3; p++) {
                int c = c0 + p * 128;
                if (c < H) {
                    float v0 = bfu_lo(hvA[p]) + bfu_lo(tvA[p]);
                    float v1 = bfu_hi(hvA[p]) + bfu_hi(tvA[p]);
                    if (v0 > 0.0f) a0[p] += v0;
                    if (v1 > 0.0f) a1[p] += v1;
                    float w0 = bfu_lo(hvB[p]) + bfu_lo(tvB[p]);
                    float w1 = bfu_hi(hvB[p]) + bfu_hi(tvB[p]);
                    if (w0 > 0.0f) a0[p] += w0;
                    if (w1 > 0.0f) a1[p] += w1;
                }
            }
        }
        if (e < e1) {
            int s = esrc[e], a = eea[e];
            const unsigned short* hr = (const unsigned short*)h + (size_t)s * H;
            const unsigned short* tr = (const unsigned short*)tblb + (size_t)a * KP1;
            #pragma unroll
            for (int p = 0; p < 3; p++) {
                int c = c0 + p * 128;
                if (c < H) {
                    unsigned hv = *(const unsigned*)(hr + c);
                    unsigned tv = *(const unsigned*)(tr + c);
                    float v0 = bfu_lo(hv) + bfu_lo(tv);
                    float v1 = bfu_hi(hv) + bfu_hi(tv);
                    if (v0 > 0.0f) a0[p] += v0;
                    if (v1 > 0.0f) a1[p] += v1;
                }
            }
        }
        const unsigned short* hn = (const unsigned short*)h + (size_t)n * H;
        unsigned short* zr = (unsigned short*)zb + (size_t)n * KP1;
        #pragma unroll
        for (int p = 0; p < 3; p++) {
            int c = c0 + p * 128;
            if (c < KP1) {
                float z0 = 0.f, z1 = 0.f;
                if (c < H) {
                    unsigned hv = *(const unsigned*)(hn + c);
                    z0 = epl * bfu_lo(hv) + a0[p];
                    z1 = epl * bfu_hi(hv) + a1[p];
                }
                *(unsigned*)(zr + c) = packbf(z0, z1);
            }
        }
    }
}

// CSR pooling (batch sorted), packed pairs, 4-node software pipeline.
// R21: also emits vninb = bf16(hp + vn) for the NEXT layer's vn MLP
// (vn is already final for the next layer when pool runs; bit-exact fusion
// of the former k_add_castpad). vninb pad columns are zeroed once at init.
__global__ __launch_bounds__(256)
void k_pool_csr(const int* __restrict__ goff, const bf16* __restrict__ h,
                float* __restrict__ hp, bf16* __restrict__ hps, int layer, int KPS,
                const float* __restrict__ vn, bf16* __restrict__ vninb, int KP1,
                int H, int G) {
    int j = threadIdx.x;
    int c = 2 * j;
    if (c >= H) return;
    for (int g = blockIdx.x; g < G; g += gridDim.x) {
        float s0 = 0.0f, s1 = 0.0f;
        int n0 = goff[g], n1 = goff[g + 1];
        const unsigned short* hb = (const unsigned short*)h;
        int n = n0;
        for (; n + 3 < n1; n += 4) {
            unsigned hv0 = *(const unsigned*)(hb + (size_t)(n + 0) * H + c);
            unsigned hv1 = *(const unsigned*)(hb + (size_t)(n + 1) * H + c);
            unsigned hv2 = *(const unsigned*)(hb + (size_t)(n + 2) * H + c);
            unsigned hv3 = *(const unsigned*)(hb + (size_t)(n + 3) * H + c);
            s0 += bfu_lo(hv0); s1 += bfu_hi(hv0);
            s0 += bfu_lo(hv1); s1 += bfu_hi(hv1);
            s0 += bfu_lo(hv2); s1 += bfu_hi(hv2);
            s0 += bfu_lo(hv3); s1 += bfu_hi(hv3);
        }
        for (; n < n1; n++) {
            unsigned hv = *(const unsigned*)(hb + (size_t)n * H + c);
            s0 += bfu_lo(hv);
            s1 += bfu_hi(hv);
        }
        hp[(size_t)g * H + c] = s0;
        hp[(size_t)g * H + c + 1] = s1;
        *(unsigned*)((unsigned short*)hps + (size_t)g * KPS + layer * H + c) = packbf(s0, s1);
        const float* vr = vn + (size_t)g * H + c;
        *(unsigned*)((unsigned short*)vninb + (size_t)g * KP1 + c) =
            packbf(s0 + vr[0], s1 + vr[1]);
    }
}

// h[n][c..c+1] += vn[batch[n]][c..c+1]   (pair-packed)
__global__ void k_addvn(bf16* __restrict__ h, const float* __restrict__ vn,
                        const int* __restrict__ batch, int H, int total2) {
    int stride = gridDim.x * blockDim.x;
    int HP = H >> 1;
    for (int i = blockIdx.x * blockDim.x + threadIdx.x; i < total2; i += stride) {
        int n = i / HP, p = i - n * HP;
        int c = 2 * p;
        unsigned short* hr = (unsigned short*)h + (size_t)n * H + c;
        unsigned hv = *(unsigned*)hr;
        const float* vr = vn + (size_t)batch[n] * H + c;
        *(unsigned*)hr = packbf(bfu_lo(hv) + vr[0], bfu_hi(hv) + vr[1]);
    }
}

// weight cast + zero-pad for L layers: dst[l][r][c] (L x Rp x Kp)
__global__ void k_castw_all(const float* __restrict__ W, bf16* __restrict__ Wb,
                            int L, int R, int K, int Kp, int total) {
    int stride = gridDim.x * blockDim.x;
    int perL = R * K;
    for (int i = blockIdx.x * blockDim.x + threadIdx.x; i < total; i += stride) {
        int RpKp = total / L;
        int l = i / RpKp, rem = i - l * RpKp;
        int r = rem / Kp, c = rem - r * Kp;
        float v = (r < R && c < K) ? W[(size_t)l * perL + (size_t)r * K + c] : 0.0f;
        Wb[i] = __float2bfloat16(v);
    }
}

// stacked pooling weight: Wb[r][c] (Rp x KPS), value = Wp[c/H][r][c%H]
__global__ void k_castWps(const float* __restrict__ Wp, bf16* __restrict__ Wb,
                          int L, int H, int KPS, int total) {
    int stride = gridDim.x * blockDim.x;
    for (int i = blockIdx.x * blockDim.x + threadIdx.x; i < total; i += stride) {
        int r = i / KPS, c = i - r * KPS;
        float v = 0.0f;
        if (r < H && c < L * H) {
            int li = c / H, k = c - li * H;
            v = Wp[(size_t)li * H * H + (size_t)r * H + k];
        }
        Wb[i] = __float2bfloat16(v);
    }
}

// o[j] = sum_i bp[i*H+j]
__global__ void k_sumbias(const float* __restrict__ bp, float* __restrict__ o,
                          int L, int H) {
    int j = blockIdx.x * blockDim.x + threadIdx.x;
    if (j < H) {
        float s = 0.f;
        for (int i = 0; i < L; i++) s += bp[(size_t)i * H + j];
        o[j] = s;
    }
}

// --- MFMA GEMM: out[m,n] = epi( sum_k A[m,k]*B[n,k] ), A,B bf16 k-contig.
// 512 threads / 8 waves, tile 128x128, per-wave 32x64.
// 3-buffer LDS pipeline, depth-2 prefetch, counted vmcnt(2), ONE barrier per
// K-step. XOR slot swizzle both sides. XCD-chunked block swizzle.
__global__ __launch_bounds__(512)
void k_mfma_gemm(const bf16* __restrict__ A, const bf16* __restrict__ B,
                 const float* __restrict__ bias, const float* __restrict__ bn,
                 const bf16* __restrict__ resb, bf16* __restrict__ out,
                 float* __restrict__ outf,
                 int M, int Nc, int Kp, int ldA, int ldOut, int ldPad,
                 int dosilu, int ncol) {
    __shared__ short As[3 * 128 * 32];
    __shared__ short Bs[3 * 128 * 32];
    const int nwg = gridDim.x;
    const int bid = blockIdx.x;
    const int q = nwg >> 3, r = nwg & 7;
    const int xcd = bid & 7, ii = bid >> 3;
    const int wgid = (xcd < r ? xcd * (q + 1) : r * (q + 1) + (xcd - r) * q) + ii;
    const int rb = wgid / ncol, cb = wgid - rb * ncol;
    const int bm = rb * 128, bn0 = cb * 128;

    const int tid = threadIdx.x;
    const int wave = tid >> 6, lane = tid & 63;
    const int wr = wave >> 1, wc = wave & 1;
    const int l15 = lane & 15, l4 = lane >> 4;
    const int srow = wave * 16 + (lane >> 2);
    const int sslot = lane & 3;

    f32x4 acc[2][4];
    #pragma unroll
    for (int mi = 0; mi < 2; mi++)
        #pragma unroll
        for (int ni = 0; ni < 4; ni++)
            acc[mi][ni] = (f32x4){0.f, 0.f, 0.f, 0.f};

    const int sg = (sslot ^ ((srow >> 1) & 3)) << 3;

    auto STAGE = [&](int buf, int k0) {
        GLOAD16(A + (size_t)(bm + srow) * ldA + k0 + sg, As + buf * 4096 + wave * 512);
        GLOAD16(B + (size_t)(bn0 + srow) * Kp + k0 + sg, Bs + buf * 4096 + wave * 512);
    };

    const int nt = Kp >> 5;
    STAGE(0, 0);
    if (nt > 1) STAGE(1, 32);
    for (int t = 0; t < nt; ++t) {
        if (t + 1 < nt) asm volatile("s_waitcnt vmcnt(2)" ::: "memory");
        else            asm volatile("s_waitcnt vmcnt(0)" ::: "memory");
        __builtin_amdgcn_sched_barrier(0);
        __builtin_amdgcn_s_barrier();
        __builtin_amdgcn_sched_barrier(0);
        if (t + 2 < nt) STAGE((t + 2) % 3, (t + 2) << 5);
        const short* Ab = As + (t % 3) * 4096;
        const short* Bb = Bs + (t % 3) * 4096;
        bf16x8 a[2], b[4];
        #pragma unroll
        for (int mi = 0; mi < 2; mi++) {
            int row = wr * 32 + mi * 16 + l15;
            a[mi] = *(const bf16x8*)&Ab[row * 32 + ((l4 ^ ((row >> 1) & 3)) << 3)];
        }
        #pragma unroll
        for (int ni = 0; ni < 4; ni++) {
            int row = wc * 64 + ni * 16 + l15;
            b[ni] = *(const bf16x8*)&Bb[row * 32 + ((l4 ^ ((row >> 1) & 3)) << 3)];
        }
        #pragma unroll
        for (int mi = 0; mi < 2; mi++)
            #pragma unroll
            for (int ni = 0; ni < 4; ni++)
                acc[mi][ni] = __builtin_amdgcn_mfma_f32_16x16x32_bf16(
                    a[mi], b[ni], acc[mi][ni], 0, 0, 0);
        __builtin_amdgcn_sched_barrier(0);
    }

    #pragma unroll
    for (int ni = 0; ni < 4; ni++) {
        int col = bn0 + wc * 64 + ni * 16 + l15;
        if (col >= ldPad) continue;
        bool pad = (col >= Nc);
        float bi = (!pad && bias) ? bias[col] : 0.f;
        float sc = 1.f, mm = 0.f, bb = 0.f;
        if (!pad && bn) {
            sc = bn[col] * rsqrtf(bn[3 * Nc + col] + 1e-5f);
            mm = bn[2 * Nc + col];
            bb = bn[Nc + col];
        }
        #pragma unroll
        for (int mi = 0; mi < 2; mi++) {
            #pragma unroll
            for (int rr = 0; rr < 4; rr++) {
                int row = bm + wr * 32 + mi * 16 + l4 * 4 + rr;
                if (row >= M) continue;
                size_t idx = (size_t)row * ldOut + col;
                if (outf) {
                    if (pad) continue;
                    float v = acc[mi][ni][rr] + bi;
                    if (bn) v = (v - mm) * sc + bb;
                    if (dosilu) v = silu_f(v);
                    outf[idx] = v;
                } else {
                    if (pad) { out[idx] = __float2bfloat16(0.f); continue; }
                    float v = acc[mi][ni][rr] + bi;
                    if (bn) v = (v - mm) * sc + bb;
                    if (dosilu) v = silu_f(v);
                    if (resb) v += __bfloat162float(resb[idx]);
                    out[idx] = __float2bfloat16(v);
                }
            }
        }
    }
}

// --- small fp32 GEMM (readout only)
#define GBM 64
#define GBN 64
#define GBK 16
__global__ __launch_bounds__(256)
void k_gemm(const float* __restrict__ A, const float* __restrict__ B,
            const float* __restrict__ bias, const float* __restrict__ bn,
            float* __restrict__ C, int M, int Nc, int K, int flags) {
    __shared__ float As[GBK][GBM + 4];
    __shared__ float Bs[GBK][GBN + 4];
    const int bm = blockIdx.x * GBM;
    const int bnc = blockIdx.y * GBN;
    const int tid = threadIdx.x;
    const int tx = tid & 15, ty = tid >> 4;
    const int ar = tid >> 2;
    const int ak = (tid & 3) << 2;

    float acc[4][4] = {{0.f}};

    for (int k0 = 0; k0 < K; k0 += GBK) {
        {
            int gr = bm + ar, gk = k0 + ak;
            float4 v = make_float4(0.f, 0.f, 0.f, 0.f);
            if (gr < M && gk < K) {
                const float* p = A + (size_t)gr * K;
                if (gk + 3 < K) v = *(const float4*)(p + gk);
                else {
                    v.x = p[gk];
                    if (gk + 1 < K) v.y = p[gk + 1];
                    if (gk + 2 < K) v.z = p[gk + 2];
                }
            }
            As[ak][ar] = v.x; As[ak + 1][ar] = v.y; As[ak + 2][ar] = v.z; As[ak + 3][ar] = v.w;
        }
        {
            int gr = bnc + ar, gk = k0 + ak;
            float4 v = make_float4(0.f, 0.f, 0.f, 0.f);
            if (gr < Nc && gk < K) {
                const float* p = B + (size_t)gr * K;
                if (gk + 3 < K) v = *(const float4*)(p + gk);
                else {
                    v.x = p[gk];
                    if (gk + 1 < K) v.y = p[gk + 1];
                    if (gk + 2 < K) v.z = p[gk + 2];
                }
            }
            Bs[ak][ar] = v.x; Bs[ak + 1][ar] = v.y; Bs[ak + 2][ar] = v.z; Bs[ak + 3][ar] = v.w;
        }
        __syncthreads();
        #pragma unroll
        for (int kk = 0; kk < GBK; kk++) {
            float4 a = *(const float4*)&As[kk][ty * 4];
            float4 b = *(const float4*)&Bs[kk][tx * 4];
            acc[0][0] += a.x * b.x; acc[0][1] += a.x * b.y; acc[0][2] += a.x * b.z; acc[0][3] += a.x * b.w;
            acc[1][0] += a.y * b.x; acc[1][1] += a.y * b.y; acc[1][2] += a.y * b.z; acc[1][3] += a.y * b.w;
            acc[2][0] += a.z * b.x; acc[2][1] += a.z * b.y; acc[2][2] += a.z * b.z; acc[2][3] += a.z * b.w;
            acc[3][0] += a.w * b.x; acc[3][1] += a.w * b.y; acc[3][2] += a.w * b.z; acc[3][3] += a.w * b.w;
        }
        __syncthreads();
    }

    #pragma unroll
    for (int i = 0; i < 4; i++) {
        int row = bm + ty * 4 + i;
        if (row >= M) continue;
        #pragma unroll
        for (int j = 0; j < 4; j++) {
            int col = bnc + tx * 4 + j;
            if (col >= Nc) continue;
            float v = acc[i][j];
            if (bias) v += bias[col];
            if (bn) {
                float g = bn[col], bb = bn[Nc + col], mm = bn[2 * Nc + col], vv = bn[3 * Nc + col];
                v = (v - mm) * (g * rsqrtf(vv + 1e-5f)) + bb;
            }
            if (flags & 1) v = silu_f(v);
            size_t idx = (size_t)row * Nc + col;
            if (flags & 2) C[idx] += v;
            else           C[idx] = v;
        }
    }
}

// per-row LayerNorm + SiLU
__global__ __launch_bounds__(256)
void k_ln_silu(const float* __restrict__ hg, const float* __restrict__ g,
               const float* __restrict__ b, float* __restrict__ r, int H) {
    int gi = blockIdx.x;
    const float* row = hg + (size_t)gi * H;
    float s = 0.f, s2 = 0.f;
    for (int j = threadIdx.x; j < H; j += blockDim.x) {
        float v = row[j];
        s += v; s2 += v * v;
    }
    for (int off = 32; off; off >>= 1) {
        s += __shfl_down(s, off);
        s2 += __shfl_down(s2, off);
    }
    __shared__ float rs[4], rs2[4];
    int wid = threadIdx.x >> 6, lane = threadIdx.x & 63;
    if (lane == 0) { rs[wid] = s; rs2[wid] = s2; }
    __syncthreads();
    if (threadIdx.x == 0) {
        float S = 0.f, S2 = 0.f;
        for (int w = 0; w < 4; w++) { S += rs[w]; S2 += rs2[w]; }
        rs[0] = S; rs2[0] = S2;
    }
    __syncthreads();
    float mu = rs[0] / H;
    float var = rs2[0] / H - mu * mu;
    float inv = rsqrtf(var + 1e-5f);
    for (int j = threadIdx.x; j < H; j += blockDim.x) {
        float v = (row[j] - mu) * inv * g[j] + b[j];
        r[(size_t)gi * H + j] = silu_f(v);
    }
}

__global__ void k_head2(const float* __restrict__ r2, const float* __restrict__ w,
                        const float* __restrict__ b, float* __restrict__ out, int Kh) {
    int gi = blockIdx.x;
    int t = threadIdx.x;
    float s = 0.f;
    for (int k = t; k < Kh; k += 64) s += r2[(size_t)gi * Kh + k] * w[k];
    for (int off = 32; off; off >>= 1) s += __shfl_down(s, off);
    if (t == 0) out[gi] = s + b[0];
}

extern "C" void kernel_launch(void* const* d_in, const int* in_sizes, int n_in,
                              void* d_out, int out_size, void* d_ws, size_t ws_size,
                              hipStream_t stream) {
    const int*   x         = (const int*)d_in[0];
    const int*   edge_attr = (const int*)d_in[1];
    const int*   eidx      = (const int*)d_in[2];
    const int*   batch     = (const int*)d_in[3];
    const float* atom_emb  = (const float*)d_in[5];
    const float* bond_emb  = (const float*)d_in[6];
    const float* We  = (const float*)d_in[7];
    const float* be  = (const float*)d_in[8];
    const float* W1  = (const float*)d_in[9];
    const float* b1  = (const float*)d_in[10];
    const float* bn1 = (const float*)d_in[11];
    const float* W2  = (const float*)d_in[12];
    const float* b2  = (const float*)d_in[13];
    const float* bn2 = (const float*)d_in[14];
    const float* epsp= (const float*)d_in[15];
    const float* Wp  = (const float*)d_in[16];
    const float* bp  = (const float*)d_in[17];
    const float* vnW1= (const float*)d_in[18];
    const float* vnb1= (const float*)d_in[19];
    const float* vnbn= (const float*)d_in[20];
    const float* vnW2= (const float*)d_in[21];
    const float* vnb2= (const float*)d_in[22];
    const float* ln_g= (const float*)d_in[23];
    const float* ln_b= (const float*)d_in[24];
    const float* hW1 = (const float*)d_in[25];
    const float* hb1 = (const float*)d_in[26];
    const float* hW2 = (const float*)d_in[27];
    const float* hb2 = (const float*)d_in[28];
    float* out = (float*)d_out;

    const int N  = in_sizes[0];
    const int E  = in_sizes[1];
    const int G  = out_size;
    const int L  = in_sizes[15];
    const int H  = in_sizes[19];
    const int H2 = 2 * H;
    const int ED = in_sizes[7] / (L * H);
    const int BV = in_sizes[6] / ED;
    const int HH = in_sizes[26];
    (void)n_in;

    const int* src = eidx;
    const int* dst = eidx + E;

    // padded dims for MFMA path
    const int KP1 = ((H  + 31) / 32) * 32;            // 320
    const int KP2 = ((H2 + 31) / 32) * 32;            // 608
    const int KPS = ((L * H + 31) / 32) * 32;         // 1504
    const int RP1 = ((H2 + 127) / 128) * 128;         // 640
    const int RP2 = ((H  + 127) / 128) * 128;         // 384
    const int Npad = ((N + 127) / 128) * 128;
    const int GP   = ((G + 127) / 128) * 128;         // 4096

    // ---- workspace carve-up (bytes, 256B aligned), strictly within ws_size ----
    char* wsb = (char*)d_ws;
    auto alb = [](size_t v) { return (v + 255) & ~(size_t)255; };
    const size_t fN = (size_t)N * H;
    const size_t fG = (size_t)G * H;

    size_t off = 0;
    bf16*  hbf   = (bf16*) (wsb + off); off += alb(fN * 2);
    bf16*  zb    = (bf16*) (wsb + off); off += alb((size_t)Npad * KP1 * 2);
    float* hp    = (float*)(wsb + off); off += alb(fG * 4);
    float* hg    = (float*)(wsb + off); off += alb(fG * 4);
    float* vn    = (float*)(wsb + off); off += alb(fG * 4);
    float* rbuf  = (float*)(wsb + off); off += alb(fG * 4);
    float* r2    = (float*)(wsb + off); off += alb((size_t)G * HH * 4);
    bf16*  tblb  = (bf16*) (wsb + off); off += alb((size_t)L * BV * KP1 * 2);
    float* bsumf = (float*)(wsb + off); off += alb((size_t)RP2 * 4);
    bf16*  W1b   = (bf16*) (wsb + off); off += alb((size_t)L * RP1 * KP1 * 2);
    bf16*  W2b   = (bf16*) (wsb + off); off += alb((size_t)L * RP2 * KP2 * 2);
    bf16*  vnW1b = (bf16*) (wsb + off); off += alb((size_t)RP2 * KP1 * 2);
    bf16*  vnW2b = (bf16*) (wsb + off); off += alb((size_t)RP2 * KP1 * 2);
    bf16*  Wpsb  = (bf16*) (wsb + off); off += alb((size_t)RP2 * KPS * 2);
    bf16*  hps   = (bf16*) (wsb + off); off += alb((size_t)GP * KPS * 2);
    bf16*  vninb = (bf16*) (wsb + off); off += alb((size_t)GP * KP1 * 2);
    bf16*  vntb  = (bf16*) (wsb + off); off += alb((size_t)GP * KP1 * 2);
    // CSR arrays (ints)
    int* eoff = (int*)(wsb + off); off += alb((size_t)(N + 1) * 4);
    int* ecur = (int*)(wsb + off); off += alb((size_t)N * 4);
    int* esrc = (int*)(wsb + off); off += alb((size_t)E * 4);
    int* eea  = (int*)(wsb + off); off += alb((size_t)E * 4);
    int* goff = (int*)(wsb + off); off += alb((size_t)(G + 1) * 4);
    int* gcnt = (int*)(wsb + off); off += alb((size_t)G * 4);
    int* bsum = (int*)(wsb + off); off += alb(1024 * 4);

    // t1 chunk region gets the rest
    size_t left = (ws_size > off + 256) ? (ws_size - off - 256) : 0;
    long long chl = (long long)(left / ((size_t)KP2 * 2));
    int CH = (int)((chl > Npad) ? Npad : chl);
    CH = (CH / 128) * 128;
    if (CH < 128) {
        k_fill<<<64, 256, 0, stream>>>(out, 10000.0f + (float)(ws_size >> 20), G);
        return;
    }
    bf16* t1 = (bf16*)(wsb + off);

    auto gemm_f = [&](const float* A, const float* B, const float* bias, const float* bn,
                      float* C, int M, int Nc, int K, int flags) {
        dim3 grid((M + GBM - 1) / GBM, (Nc + GBN - 1) / GBN);
        k_gemm<<<grid, dim3(256), 0, stream>>>(A, B, bias, bn, C, M, Nc, K, flags);
    };
    auto mfma = [&](const bf16* A, const bf16* B, const float* bias, const float* bn,
                    const bf16* resb, bf16* outb, float* outf, int M, int Nc, int Kp,
                    int ldA, int ldOut, int ldPad, int dosilu, int ncolT) {
        int mt = (M + 127) / 128;
        k_mfma_gemm<<<dim3(mt * ncolT), dim3(512), 0, stream>>>(
            A, B, bias, bn, resb, outb, outf, M, Nc, Kp, ldA, ldOut, ldPad, dosilu, ncolT);
    };
    auto zero = [&](void* p, size_t nfloats) { k_zero<<<1024, 256, 0, stream>>>((float*)p, nfloats); };

    const int NH = N * H;

    // ---- CSR builds (dst and batch are layer-invariant) ----
    {
        int nb = (N + 1023) / 1024;
        zero(ecur, N);
        k_hist<<<1024, 256, 0, stream>>>(dst, ecur, E);
        k_scan1<<<nb, 256, 0, stream>>>(ecur, eoff, bsum, N);
        k_scan1<<<1, 256, 0, stream>>>(bsum, bsum, nullptr, nb);
        k_scan_add<<<512, 256, 0, stream>>>(eoff, bsum, ecur, N, E);
        k_escatter<<<1024, 256, 0, stream>>>(dst, src, edge_attr, ecur, esrc, eea, E);

        int nbg = (G + 1023) / 1024;
        zero(gcnt, G);
        k_hist<<<1024, 256, 0, stream>>>(batch, gcnt, N);
        k_scan1<<<nbg, 256, 0, stream>>>(gcnt, goff, bsum, G);
        k_scan1<<<1, 256, 0, stream>>>(bsum, bsum, nullptr, nbg);
        k_scan_add<<<64, 256, 0, stream>>>(goff, bsum, nullptr, G, N);
    }

    zero(vn, fG);
    zero(hps, (size_t)GP * KPS / 2);    // bf16 buffer: bytes/4 floats
    zero(vninb, (size_t)GP * KP1 / 2);  // covers pad cols + tail rows once

    k_eptable<<<L * BV, 320, 0, stream>>>(bond_emb, We, be, tblb, BV, H, ED, KP1);
    k_encode<<<2048, 256, 0, stream>>>(x, atom_emb, hbf, H, NH);
    // weight casts (once per launch)
    k_castw_all<<<2048, 256, 0, stream>>>(W1, W1b, L, H2, H, KP1, L * RP1 * KP1);
    k_castw_all<<<2048, 256, 0, stream>>>(W2, W2b, L, H, H2, KP2, L * RP2 * KP2);
    k_castw_all<<<256, 256, 0, stream>>>(vnW1, vnW1b, 1, H, H, KP1, RP2 * KP1);
    k_castw_all<<<256, 256, 0, stream>>>(vnW2, vnW2b, 1, H, H, KP1, RP2 * KP1);
    k_castWps<<<512, 256, 0, stream>>>(Wp, Wpsb, L, H, KPS, RP2 * KPS);
    k_sumbias<<<(H + 255) / 256, 256, 0, stream>>>(bp, bsumf, L, H);

    for (int i = 0; i < L; i++) {
        if (i > 0) {
            // vn MLP on MFMA path (vninb emitted by previous layer's pool)
            mfma(vninb, vnW1b, vnb1, vnbn, nullptr, vntb, nullptr,
                 G, H, KP1, KP1, KP1, KP1, 1, RP2 / 128);
            mfma(vntb, vnW2b, vnb2, nullptr, nullptr, nullptr, vn,
                 G, H, KP1, KP1, H, H, 0, RP2 / 128);
            k_addvn<<<2048, 256, 0, stream>>>(hbf, vn, batch, H, N * (H >> 1));
        }
        // fused message + zmix (one wave per node, packed loads, 2-edge pipeline)
        k_msg_csr<<<4096, 256, 0, stream>>>(eoff, esrc, eea, hbf,
                                            tblb + (size_t)i * BV * KP1, epsp, i,
                                            zb, H, KP1, N);
        // node MLP, row-chunked through t1
        for (int r0 = 0; r0 < N; r0 += CH) {
            int m = (N - r0 < CH) ? (N - r0) : CH;
            mfma(zb + (size_t)r0 * KP1, W1b + (size_t)i * RP1 * KP1,
                 b1 + (size_t)i * H2, bn1 + (size_t)i * 4 * H2,
                 nullptr, t1, nullptr, m, H2, KP1, KP1, KP2, KP2, 1, RP1 / 128);
            mfma(t1, W2b + (size_t)i * RP2 * KP2, b2 + (size_t)i * H,
                 bn2 + (size_t)i * 4 * H,
                 (i > 0) ? (hbf + (size_t)r0 * H) : nullptr, hbf + (size_t)r0 * H,
                 nullptr, m, H, KP2, KP2, H, H, 1, RP2 / 128);
        }
        // CSR pooling: hp fp32 + bf16 slices into hps and vninb (fused castpad)
        k_pool_csr<<<4096, 256, 0, stream>>>(goff, hbf, hp, hps, i, KPS,
                                             vn, vninb, KP1, H, G);
    }

    // hg = hps @ Wps^T + sum(bp)  (single stacked GEMM, fp32 out)
    mfma(hps, Wpsb, bsumf, nullptr, nullptr, nullptr, hg,
         G, H, KPS, KPS, H, H, 0, RP2 / 128);

    // readout
    k_ln_silu<<<G, 256, 0, stream>>>(hg, ln_g, ln_b, rbuf, H);
    gemm_f(rbuf, hW1, hb1, nullptr, r2, G, HH, H, 1);
    k_head2<<<G, 64, 0, stream>>>(r2, hW2, hb2, out, HH);
}